// Round 1
// baseline (359.858 us; speedup 1.0000x reference)
//
#include <hip/hip_runtime.h>
#include <hip/hip_bf16.h>
#include <cstdint>
#include <cstddef>

typedef __bf16 bf16;
typedef __bf16 bf16x8 __attribute__((ext_vector_type(8)));
typedef float f32x4 __attribute__((ext_vector_type(4)));

#define S_LEN 2048
#define DM 1024
#define NH 16
#define HD 64
// (1/sqrt(64)) * log2(e): fold softmax scale + exp2 conversion into Q
#define QK_SCALE 0.18033688011112042f

__device__ __forceinline__ void gload_lds16(const bf16* g, bf16* l) {
  __builtin_amdgcn_global_load_lds(
      (const __attribute__((address_space(1))) void*)g,
      (__attribute__((address_space(3))) void*)l, 16, 0, 0);
}

// ---------------- fp32 -> bf16 convert (vectorized) ----------------
__global__ void cvt_f32_bf16(const float* __restrict__ in, bf16* __restrict__ out, int n) {
  int i = (blockIdx.x * 256 + threadIdx.x) * 8;
  if (i >= n) return;
  const float4 a = *(const float4*)(in + i);
  const float4 b = *(const float4*)(in + i + 4);
  bf16x8 o;
  o[0] = (bf16)a.x; o[1] = (bf16)a.y; o[2] = (bf16)a.z; o[3] = (bf16)a.w;
  o[4] = (bf16)b.x; o[5] = (bf16)b.y; o[6] = (bf16)b.z; o[7] = (bf16)b.w;
  *(bf16x8*)(out + i) = o;
}

// ---------------- GEMM: Y[m,n] = sum_k A[m,k] * W[n,k] + bias[n] ----------------
// A: [M,K] bf16 row-major. W: [N,K] bf16 row-major (torch Linear weight).
// MODE 0: out bf16, head-major [B,H,S,hd]   (for Q with scale, K with scale=1)
// MODE 1: out bf16, per-head transposed [B,H,hd,S]  (for V)
// MODE 2: out fp32, row-major [M,N]         (final projection)
// 128x128 tile, BK=64, 256 threads (4 waves, 2x2), m97 structure.
template <int MODE>
__global__ void gemm_bt(const bf16* __restrict__ A, const bf16* __restrict__ W,
                        const float* __restrict__ bias, void* __restrict__ Out,
                        int M, int N, int K, float scale) {
  __shared__ __align__(16) bf16 Asl[128 * 64];
  __shared__ __align__(16) bf16 Bsl[128 * 64];
  const int tid = threadIdx.x;
  const int lane = tid & 63, w = tid >> 6;
  const int wr = w >> 1, wc = w & 1;
  const int r16 = lane & 15, grp = lane >> 4;
  const int m0 = blockIdx.y * 128, n0 = blockIdx.x * 128;

  f32x4 acc[4][4] = {};

  const int nk = K >> 6;
  for (int t = 0; t < nk; ++t) {
    const int k0 = t << 6;
    __syncthreads();  // protect LDS from previous iteration's readers
#pragma unroll
    for (int j = 0; j < 4; ++j) {
      const int lin = j * 256 + tid;
      const int rr = lin >> 3;         // tile row 0..127
      const int cc = (lin & 7) * 8;    // k-offset within 64
      gload_lds16(&A[(size_t)(m0 + rr) * K + k0 + cc], &Asl[lin * 8]);
      gload_lds16(&W[(size_t)(n0 + rr) * K + k0 + cc], &Bsl[lin * 8]);
    }
    __syncthreads();  // drains vmcnt: staged data visible
#pragma unroll
    for (int kk = 0; kk < 2; ++kk) {
      bf16x8 af[4], bfr[4];
#pragma unroll
      for (int m = 0; m < 4; ++m)
        af[m] = *(const bf16x8*)&Asl[(wr * 64 + m * 16 + r16) * 64 + kk * 32 + grp * 8];
#pragma unroll
      for (int n = 0; n < 4; ++n)
        bfr[n] = *(const bf16x8*)&Bsl[(wc * 64 + n * 16 + r16) * 64 + kk * 32 + grp * 8];
#pragma unroll
      for (int m = 0; m < 4; ++m)
#pragma unroll
        for (int n = 0; n < 4; ++n)
          acc[m][n] = __builtin_amdgcn_mfma_f32_16x16x32_bf16(af[m], bfr[n], acc[m][n], 0, 0, 0);
    }
  }

  // epilogue: D frag -> col = lane&15, row = (lane>>4)*4 + r
#pragma unroll
  for (int m = 0; m < 4; ++m) {
#pragma unroll
    for (int n = 0; n < 4; ++n) {
#pragma unroll
      for (int r = 0; r < 4; ++r) {
        const int row = m0 + wr * 64 + m * 16 + grp * 4 + r;
        const int col = n0 + wc * 64 + n * 16 + r16;
        const float v = (acc[m][n][r] + bias[col]) * scale;
        if (MODE == 0) {
          const int b = row >> 11, s = row & 2047, h = col >> 6, d = col & 63;
          ((bf16*)Out)[((size_t)(b * NH + h) * S_LEN + s) * HD + d] = (bf16)v;
        } else if (MODE == 1) {
          const int b = row >> 11, s = row & 2047, h = col >> 6, d = col & 63;
          ((bf16*)Out)[((size_t)(b * NH + h) * HD + d) * S_LEN + s] = (bf16)v;
        } else {
          ((float*)Out)[(size_t)row * N + col] = v;
        }
      }
    }
  }
}

// ---------------- causal flash attention ----------------
// Qh,Kh: [B,H,S,hd] bf16 (Q pre-scaled by QK_SCALE). Vt: [B,H,hd,S] bf16.
// AO: [B,S,D] bf16. Block = 64 q-rows of one (b,h); 4 waves x 16 rows.
__global__ void attn_fwd(const bf16* __restrict__ Qh, const bf16* __restrict__ Kh,
                         const bf16* __restrict__ Vt, bf16* __restrict__ AO) {
  __shared__ __align__(16) bf16 Pl[4][16][80];  // per-wave P buffer, padded pitch
  const int tid = threadIdx.x;
  const int lane = tid & 63, w = tid >> 6;
  const int r16 = lane & 15, grp = lane >> 4;
  const int q0 = blockIdx.x * 64;
  const int bh = blockIdx.z * NH + blockIdx.y;
  const bf16* Qb = Qh + (size_t)bh * S_LEN * HD;
  const bf16* Kb = Kh + (size_t)bh * S_LEN * HD;
  const bf16* Vb = Vt + (size_t)bh * HD * S_LEN;

  const int qrow = q0 + w * 16;
  bf16x8 qf[2];
#pragma unroll
  for (int kk = 0; kk < 2; ++kk)
    qf[kk] = *(const bf16x8*)&Qb[(size_t)(qrow + r16) * HD + kk * 32 + grp * 8];

  f32x4 accO[4] = {};
  float mr[4], lr[4];
#pragma unroll
  for (int r = 0; r < 4; ++r) { mr[r] = -1e30f; lr[r] = 0.f; }

  const int ntiles = blockIdx.x + 1;
  for (int kt = 0; kt < ntiles; ++kt) {
    const int k0 = kt * 64;
    f32x4 s[4] = {};
#pragma unroll
    for (int kk = 0; kk < 2; ++kk) {
#pragma unroll
      for (int n = 0; n < 4; ++n) {
        bf16x8 kf = *(const bf16x8*)&Kb[(size_t)(k0 + n * 16 + r16) * HD + kk * 32 + grp * 8];
        s[n] = __builtin_amdgcn_mfma_f32_16x16x32_bf16(qf[kk], kf, s[n], 0, 0, 0);
      }
    }
    if (kt == ntiles - 1) {  // diagonal tile: causal mask
#pragma unroll
      for (int n = 0; n < 4; ++n)
#pragma unroll
        for (int r = 0; r < 4; ++r) {
          const int key = k0 + n * 16 + r16;
          const int q = qrow + grp * 4 + r;
          if (key > q) s[n][r] = -1e30f;
        }
    }
    // row max over 64 keys: 4 frags in-lane, then 16-lane butterfly
    float ps[4];
#pragma unroll
    for (int r = 0; r < 4; ++r) {
      float x = fmaxf(fmaxf(s[0][r], s[1][r]), fmaxf(s[2][r], s[3][r]));
      x = fmaxf(x, __shfl_xor(x, 1));
      x = fmaxf(x, __shfl_xor(x, 2));
      x = fmaxf(x, __shfl_xor(x, 4));
      x = fmaxf(x, __shfl_xor(x, 8));
      const float mn = fmaxf(mr[r], x);
      const float alpha = exp2f(mr[r] - mn);
      mr[r] = mn;
      lr[r] *= alpha;
#pragma unroll
      for (int nd = 0; nd < 4; ++nd) accO[nd][r] *= alpha;
      float psum = 0.f;
#pragma unroll
      for (int n = 0; n < 4; ++n) {
        const float p = exp2f(s[n][r] - mn);
        psum += p;
        Pl[w][grp * 4 + r][n * 16 + r16] = (bf16)p;
      }
      ps[r] = psum;
    }
#pragma unroll
    for (int r = 0; r < 4; ++r) {
      float x = ps[r];
      x += __shfl_xor(x, 1);
      x += __shfl_xor(x, 2);
      x += __shfl_xor(x, 4);
      x += __shfl_xor(x, 8);
      lr[r] += x;
    }
    // PV: A-frag = P rows (lane&15), B-frag = Vt[d][k] (K-contiguous)
#pragma unroll
    for (int kk = 0; kk < 2; ++kk) {
      bf16x8 pf = *(const bf16x8*)&Pl[w][r16][kk * 32 + grp * 8];
#pragma unroll
      for (int nd = 0; nd < 4; ++nd) {
        bf16x8 vf = *(const bf16x8*)&Vb[(size_t)(nd * 16 + r16) * S_LEN + k0 + kk * 32 + grp * 8];
        accO[nd] = __builtin_amdgcn_mfma_f32_16x16x32_bf16(pf, vf, accO[nd], 0, 0, 0);
      }
    }
  }

  const int b = bh >> 4, h = bh & 15;
#pragma unroll
  for (int nd = 0; nd < 4; ++nd)
#pragma unroll
    for (int r = 0; r < 4; ++r) {
      const int q = qrow + grp * 4 + r;
      const int d = nd * 16 + r16;
      AO[((size_t)(b * S_LEN + q)) * DM + h * HD + d] = (bf16)(accO[nd][r] / lr[r]);
    }
}

// ---------------- launch ----------------
extern "C" void kernel_launch(void* const* d_in, const int* in_sizes, int n_in,
                              void* d_out, int out_size, void* d_ws, size_t ws_size,
                              hipStream_t stream) {
  const float* q  = (const float*)d_in[0];
  const float* k  = (const float*)d_in[1];
  const float* v  = (const float*)d_in[2];
  const float* Wq = (const float*)d_in[3];
  const float* bq = (const float*)d_in[4];
  const float* Wk = (const float*)d_in[5];
  const float* bk = (const float*)d_in[6];
  const float* Wv = (const float*)d_in[7];
  const float* bv = (const float*)d_in[8];
  const float* Wo = (const float*)d_in[9];
  const float* bo = (const float*)d_in[10];

  const int NTOK = 2 * S_LEN;          // 4096
  const int NQKV = NTOK * DM;          // 4,194,304
  const int NW   = DM * DM;            // 1,048,576

  bf16* qb  = (bf16*)d_ws;
  bf16* kb  = qb + NQKV;
  bf16* vb  = kb + NQKV;
  bf16* Wqb = vb + NQKV;
  bf16* Wkb = Wqb + NW;
  bf16* Wvb = Wkb + NW;
  bf16* Wob = Wvb + NW;
  bf16* Qh  = Wob + NW;
  bf16* Kh  = Qh + NQKV;
  bf16* Vt  = Kh + NQKV;
  bf16* AO  = Vt + NQKV;

  // converts
  cvt_f32_bf16<<<NQKV / 8 / 256, 256, 0, stream>>>(q, qb, NQKV);
  cvt_f32_bf16<<<NQKV / 8 / 256, 256, 0, stream>>>(k, kb, NQKV);
  cvt_f32_bf16<<<NQKV / 8 / 256, 256, 0, stream>>>(v, vb, NQKV);
  cvt_f32_bf16<<<NW / 8 / 256, 256, 0, stream>>>(Wq, Wqb, NW);
  cvt_f32_bf16<<<NW / 8 / 256, 256, 0, stream>>>(Wk, Wkb, NW);
  cvt_f32_bf16<<<NW / 8 / 256, 256, 0, stream>>>(Wv, Wvb, NW);
  cvt_f32_bf16<<<NW / 8 / 256, 256, 0, stream>>>(Wo, Wob, NW);

  // projections: M=4096, N=1024, K=1024
  dim3 gg(DM / 128, NTOK / 128);
  gemm_bt<0><<<gg, 256, 0, stream>>>(qb, Wqb, bq, Qh, NTOK, DM, DM, QK_SCALE);
  gemm_bt<0><<<gg, 256, 0, stream>>>(kb, Wkb, bk, Kh, NTOK, DM, DM, 1.0f);
  gemm_bt<1><<<gg, 256, 0, stream>>>(vb, Wvb, bv, Vt, NTOK, DM, DM, 1.0f);

  // attention: grid (S/64, H, B)
  dim3 ga(S_LEN / 64, NH, 2);
  attn_fwd<<<ga, 256, 0, stream>>>(Qh, Kh, Vt, AO);

  // output projection -> fp32 d_out
  gemm_bt<2><<<gg, 256, 0, stream>>>(AO, Wob, bo, d_out, NTOK, DM, DM, 1.0f);
}

// Round 2
// 251.436 us; speedup vs baseline: 1.4312x; 1.4312x over previous
//
#include <hip/hip_runtime.h>
#include <hip/hip_bf16.h>
#include <cstdint>
#include <cstddef>

typedef __bf16 bf16;
typedef __bf16 bf16x2 __attribute__((ext_vector_type(2)));
typedef __bf16 bf16x4 __attribute__((ext_vector_type(4)));
typedef __bf16 bf16x8 __attribute__((ext_vector_type(8)));
typedef float f32x4 __attribute__((ext_vector_type(4)));
typedef float f32x16 __attribute__((ext_vector_type(16)));
typedef unsigned int u32x4 __attribute__((ext_vector_type(4)));

#define S_LEN 2048
#define DM 1024
#define NH 16
#define HD 64
// (1/sqrt(64)) * log2(e): fold softmax scale + exp2 conversion into Q
#define QK_SCALE 0.18033688011112042f

__device__ __forceinline__ void gload_lds16(const bf16* g, bf16* l) {
  __builtin_amdgcn_global_load_lds(
      (const __attribute__((address_space(1))) void*)g,
      (__attribute__((address_space(3))) void*)l, 16, 0, 0);
}

// pack 2 f32 -> bf16x2 word (compiler emits good code; m240: don't hand-write cvt_pk)
__device__ __forceinline__ unsigned packbf(float lo, float hi) {
  bf16x2 t;
  t[0] = (bf16)lo;
  t[1] = (bf16)hi;
  return __builtin_bit_cast(unsigned, t);
}

// v_permlane32_swap_b32: new_a[l>=32] = b_old[l-32]; new_b[l<32] = a_old[l+32]
__device__ __forceinline__ void pl32swap(unsigned& a, unsigned& b) {
#if __has_builtin(__builtin_amdgcn_permlane32_swap)
  auto r = __builtin_amdgcn_permlane32_swap((int)a, (int)b, false, false);
  a = (unsigned)r[0];
  b = (unsigned)r[1];
#else
  asm volatile("v_permlane32_swap_b32 %0, %1" : "+v"(a), "+v"(b));
#endif
}

// ---------------- fp32 -> bf16 convert (vectorized) ----------------
__global__ void cvt_f32_bf16(const float* __restrict__ in, bf16* __restrict__ out, int n) {
  int i = (blockIdx.x * 256 + threadIdx.x) * 8;
  if (i >= n) return;
  const float4 a = *(const float4*)(in + i);
  const float4 b = *(const float4*)(in + i + 4);
  bf16x8 o;
  o[0] = (bf16)a.x; o[1] = (bf16)a.y; o[2] = (bf16)a.z; o[3] = (bf16)a.w;
  o[4] = (bf16)b.x; o[5] = (bf16)b.y; o[6] = (bf16)b.z; o[7] = (bf16)b.w;
  *(bf16x8*)(out + i) = o;
}

// ---------------- GEMM: Y[m,n] = sum_k A[m,k] * W[n,k] + bias[n] ----------------
// MODE 0: out bf16, head-major [B,H,S,hd]   (Q with scale, K with scale=1)
// MODE 1: out bf16, per-head transposed [B,H,hd,S]  (V)
// MODE 2: out fp32, row-major [M,N]         (final projection)
template <int MODE>
__global__ __launch_bounds__(256, 2) void gemm_bt(
    const bf16* __restrict__ A, const bf16* __restrict__ W,
    const float* __restrict__ bias, void* __restrict__ Out,
    int M, int N, int K, float scale) {
  __shared__ __align__(16) bf16 Asl[128 * 64];
  __shared__ __align__(16) bf16 Bsl[128 * 64];
  const int tid = threadIdx.x;
  const int lane = tid & 63, w = tid >> 6;
  const int wr = w >> 1, wc = w & 1;
  const int r16 = lane & 15, grp = lane >> 4;
  const int m0 = blockIdx.y * 128, n0 = blockIdx.x * 128;

  f32x4 acc[4][4] = {};

  const int nk = K >> 6;
  for (int t = 0; t < nk; ++t) {
    const int k0 = t << 6;
    __syncthreads();
#pragma unroll
    for (int j = 0; j < 4; ++j) {
      const int lin = j * 256 + tid;
      const int rr = lin >> 3;
      const int cc = (lin & 7) * 8;
      gload_lds16(&A[(size_t)(m0 + rr) * K + k0 + cc], &Asl[lin * 8]);
      gload_lds16(&W[(size_t)(n0 + rr) * K + k0 + cc], &Bsl[lin * 8]);
    }
    __syncthreads();
#pragma unroll
    for (int kk = 0; kk < 2; ++kk) {
      bf16x8 af[4], bfr[4];
#pragma unroll
      for (int m = 0; m < 4; ++m)
        af[m] = *(const bf16x8*)&Asl[(wr * 64 + m * 16 + r16) * 64 + kk * 32 + grp * 8];
#pragma unroll
      for (int n = 0; n < 4; ++n)
        bfr[n] = *(const bf16x8*)&Bsl[(wc * 64 + n * 16 + r16) * 64 + kk * 32 + grp * 8];
#pragma unroll
      for (int m = 0; m < 4; ++m)
#pragma unroll
        for (int n = 0; n < 4; ++n)
          acc[m][n] = __builtin_amdgcn_mfma_f32_16x16x32_bf16(af[m], bfr[n], acc[m][n], 0, 0, 0);
    }
  }

#pragma unroll
  for (int m = 0; m < 4; ++m) {
#pragma unroll
    for (int n = 0; n < 4; ++n) {
#pragma unroll
      for (int r = 0; r < 4; ++r) {
        const int row = m0 + wr * 64 + m * 16 + grp * 4 + r;
        const int col = n0 + wc * 64 + n * 16 + r16;
        const float v = (acc[m][n][r] + bias[col]) * scale;
        if (MODE == 0) {
          const int b = row >> 11, s = row & 2047, h = col >> 6, d = col & 63;
          ((bf16*)Out)[((size_t)(b * NH + h) * S_LEN + s) * HD + d] = (bf16)v;
        } else if (MODE == 1) {
          const int b = row >> 11, s = row & 2047, h = col >> 6, d = col & 63;
          ((bf16*)Out)[((size_t)(b * NH + h) * HD + d) * S_LEN + s] = (bf16)v;
        } else {
          ((float*)Out)[(size_t)row * N + col] = v;
        }
      }
    }
  }
}

// ---------------- causal flash attention, swapped-operand 32x32 (m214 structure) ----
// Qh,Kh: [B,H,S,hd] bf16 (Q pre-scaled). Vt: [B,H,hd,S] bf16. AO: [B,S,D] bf16.
// Block = 4 independent waves; each wave owns 32 q-rows. No LDS, no barriers.
// QK^T swapped: mfma(A=K, B=Q) -> scores col = q = lane&31 (lane-local softmax).
// PV swapped:   mfma(A=Vt, B=P) -> O col = q = lane&31 (lane-local rescale).
__global__ __launch_bounds__(256, 2) void attn_fwd2(
    const bf16* __restrict__ Qh, const bf16* __restrict__ Kh,
    const bf16* __restrict__ Vt, bf16* __restrict__ AO) {
  const int tid = threadIdx.x;
  const int lane = tid & 63, w = tid >> 6;
  const int q31 = lane & 31, h = lane >> 5;

  // head->XCD grouping: 4 heads per XCD (K+V = 2MB, L2-resident); reversed q-tiles
  const int bid = blockIdx.x;            // 0..511
  const int xcd = bid & 7;
  const int within = bid >> 3;           // 0..63
  const int bh = xcd * 4 + (within >> 4);
  const int qt = 15 - (within & 15);
  const int q0w = qt * 128 + w * 32;

  const bf16* Qb = Qh + (size_t)bh * S_LEN * HD;
  const bf16* Kb = Kh + (size_t)bh * S_LEN * HD;
  const bf16* Vb = Vt + (size_t)bh * HD * S_LEN;
  const int qg = q0w + q31;

  // Q B-frags: col=q=lane&31, k = ks*16 + 8h + i  (contiguous in d)
  bf16x8 qf[4];
#pragma unroll
  for (int ks = 0; ks < 4; ++ks)
    qf[ks] = *(const bf16x8*)&Qb[(size_t)qg * HD + ks * 16 + 8 * h];

  f32x16 accO[2] = {};
  float m = -1e30f, l = 0.f;

  const int ntiles = (q0w >> 6) + 1;
  for (int kt = 0; kt < ntiles; ++kt) {
    const int k0 = kt << 6;
    // ---- QK^T: two 32-key blocks ----
    f32x16 p0 = {}, p1 = {};
#pragma unroll
    for (int ks = 0; ks < 4; ++ks) {
      bf16x8 kf0 = *(const bf16x8*)&Kb[(size_t)(k0 + q31) * HD + ks * 16 + 8 * h];
      bf16x8 kf1 = *(const bf16x8*)&Kb[(size_t)(k0 + 32 + q31) * HD + ks * 16 + 8 * h];
      p0 = __builtin_amdgcn_mfma_f32_32x32x16_bf16(kf0, qf[ks], p0, 0, 0, 0);
      p1 = __builtin_amdgcn_mfma_f32_32x32x16_bf16(kf1, qf[ks], p1, 0, 0, 0);
    }
    // ---- causal mask (diagonal tile only); key row = (r&3)+8*(r>>2)+4h ----
    if (kt == ntiles - 1) {
#pragma unroll
      for (int r = 0; r < 16; ++r) {
        const int key = k0 + (r & 3) + 8 * (r >> 2) + 4 * h;
        if (key > qg) p0[r] = -1e30f;
        if (key + 32 > qg) p1[r] = -1e30f;
      }
    }
    // ---- lane-local softmax: q = lane&31, other key-half in lane^32 ----
    float mt = p0[0];
#pragma unroll
    for (int r = 1; r < 16; ++r) mt = fmaxf(mt, p0[r]);
#pragma unroll
    for (int r = 0; r < 16; ++r) mt = fmaxf(mt, p1[r]);
    mt = fmaxf(mt, __shfl_xor(mt, 32));
    const float mn = fmaxf(m, mt);
    const float alpha = exp2f(m - mn);
    m = mn;
    float sum = 0.f;
#pragma unroll
    for (int r = 0; r < 16; ++r) { p0[r] = exp2f(p0[r] - mn); sum += p0[r]; }
#pragma unroll
    for (int r = 0; r < 16; ++r) { p1[r] = exp2f(p1[r] - mn); sum += p1[r]; }
    sum += __shfl_xor(sum, 32);
    l = l * alpha + sum;
#pragma unroll
    for (int r = 0; r < 16; ++r) { accO[0][r] *= alpha; accO[1][r] *= alpha; }

    // ---- pack P -> PV B-frags via permlane32_swap (T12) ----
    // B-frag word j of k-slot: keys ks*16 + 8h + 2j,2j+1 for THIS lane's h.
    unsigned pw[4][4];
#pragma unroll
    for (int bb = 0; bb < 2; ++bb) {
      unsigned wv[8];
#pragma unroll
      for (int mm = 0; mm < 8; ++mm)
        wv[mm] = bb ? packbf(p1[2 * mm], p1[2 * mm + 1])
                    : packbf(p0[2 * mm], p0[2 * mm + 1]);
      pl32swap(wv[0], wv[2]);  // -> word(ks'=0,j=0), word(ks'=0,j=2)
      pl32swap(wv[1], wv[3]);  // -> word(ks'=0,j=1), word(ks'=0,j=3)
      pl32swap(wv[4], wv[6]);  // -> word(ks'=1,j=0), word(ks'=1,j=2)
      pl32swap(wv[5], wv[7]);  // -> word(ks'=1,j=1), word(ks'=1,j=3)
      pw[bb * 2 + 0][0] = wv[0]; pw[bb * 2 + 0][1] = wv[1];
      pw[bb * 2 + 0][2] = wv[2]; pw[bb * 2 + 0][3] = wv[3];
      pw[bb * 2 + 1][0] = wv[4]; pw[bb * 2 + 1][1] = wv[5];
      pw[bb * 2 + 1][2] = wv[6]; pw[bb * 2 + 1][3] = wv[7];
    }

    // ---- PV: A = Vt rows (d), B = P; accO col = q ----
#pragma unroll
    for (int ks = 0; ks < 4; ++ks) {
      u32x4 pu = {pw[ks][0], pw[ks][1], pw[ks][2], pw[ks][3]};
      const bf16x8 pf = __builtin_bit_cast(bf16x8, pu);
#pragma unroll
      for (int db = 0; db < 2; ++db) {
        bf16x8 vf = *(const bf16x8*)&Vb[(size_t)(db * 32 + q31) * S_LEN + k0 + ks * 16 + 8 * h];
        accO[db] = __builtin_amdgcn_mfma_f32_32x32x16_bf16(vf, pf, accO[db], 0, 0, 0);
      }
    }
  }

  // ---- store: O row = d = (r&3)+8*(r>>2)+4h+32db, col = q = lane&31 ----
  const float ro = 1.0f / l;
  const int b = bh >> 4, hh = bh & 15;
  bf16* orow = AO + ((size_t)(b * S_LEN + qg)) * DM + hh * HD;
#pragma unroll
  for (int db = 0; db < 2; ++db) {
#pragma unroll
    for (int mm = 0; mm < 4; ++mm) {
      bf16x4 ov;
#pragma unroll
      for (int t = 0; t < 4; ++t) ov[t] = (bf16)(accO[db][4 * mm + t] * ro);
      *(bf16x4*)&orow[db * 32 + 8 * mm + 4 * h] = ov;
    }
  }
}

// ---------------- launch ----------------
extern "C" void kernel_launch(void* const* d_in, const int* in_sizes, int n_in,
                              void* d_out, int out_size, void* d_ws, size_t ws_size,
                              hipStream_t stream) {
  const float* q  = (const float*)d_in[0];
  const float* k  = (const float*)d_in[1];
  const float* v  = (const float*)d_in[2];
  const float* Wq = (const float*)d_in[3];
  const float* bq = (const float*)d_in[4];
  const float* Wk = (const float*)d_in[5];
  const float* bk = (const float*)d_in[6];
  const float* Wv = (const float*)d_in[7];
  const float* bv = (const float*)d_in[8];
  const float* Wo = (const float*)d_in[9];
  const float* bo = (const float*)d_in[10];

  const int NTOK = 2 * S_LEN;          // 4096
  const int NQKV = NTOK * DM;          // 4,194,304
  const int NW   = DM * DM;            // 1,048,576

  bf16* qb  = (bf16*)d_ws;
  bf16* kb  = qb + NQKV;
  bf16* vb  = kb + NQKV;
  bf16* Wqb = vb + NQKV;
  bf16* Wkb = Wqb + NW;
  bf16* Wvb = Wkb + NW;
  bf16* Wob = Wvb + NW;
  bf16* Qh  = Wob + NW;
  bf16* Kh  = Qh + NQKV;
  bf16* Vt  = Kh + NQKV;
  bf16* AO  = Vt + NQKV;

  cvt_f32_bf16<<<NQKV / 8 / 256, 256, 0, stream>>>(q, qb, NQKV);
  cvt_f32_bf16<<<NQKV / 8 / 256, 256, 0, stream>>>(k, kb, NQKV);
  cvt_f32_bf16<<<NQKV / 8 / 256, 256, 0, stream>>>(v, vb, NQKV);
  cvt_f32_bf16<<<NW / 8 / 256, 256, 0, stream>>>(Wq, Wqb, NW);
  cvt_f32_bf16<<<NW / 8 / 256, 256, 0, stream>>>(Wk, Wkb, NW);
  cvt_f32_bf16<<<NW / 8 / 256, 256, 0, stream>>>(Wv, Wvb, NW);
  cvt_f32_bf16<<<NW / 8 / 256, 256, 0, stream>>>(Wo, Wob, NW);

  dim3 gg(DM / 128, NTOK / 128);
  gemm_bt<0><<<gg, 256, 0, stream>>>(qb, Wqb, bq, Qh, NTOK, DM, DM, QK_SCALE);
  gemm_bt<0><<<gg, 256, 0, stream>>>(kb, Wkb, bk, Kh, NTOK, DM, DM, 1.0f);
  gemm_bt<1><<<gg, 256, 0, stream>>>(vb, Wvb, bv, Vt, NTOK, DM, DM, 1.0f);

  attn_fwd2<<<dim3(512), 256, 0, stream>>>(Qh, Kh, Vt, AO);

  gemm_bt<2><<<gg, 256, 0, stream>>>(AO, Wob, bo, d_out, NTOK, DM, DM, 1.0f);
}

// Round 3
// 187.198 us; speedup vs baseline: 1.9223x; 1.3432x over previous
//
#include <hip/hip_runtime.h>
#include <hip/hip_bf16.h>
#include <cstdint>
#include <cstddef>

typedef __bf16 bf16;
typedef __bf16 bf16x2 __attribute__((ext_vector_type(2)));
typedef __bf16 bf16x4 __attribute__((ext_vector_type(4)));
typedef __bf16 bf16x8 __attribute__((ext_vector_type(8)));
typedef float f32x4 __attribute__((ext_vector_type(4)));
typedef float f32x16 __attribute__((ext_vector_type(16)));
typedef unsigned int u32x4 __attribute__((ext_vector_type(4)));

#define S_LEN 2048
#define DM 1024
#define NH 16
#define HD 64
#define NQKV (4096 * 1024)   // tokens * DM
#define NW (1024 * 1024)
// (1/sqrt(64)) * log2(e): fold softmax scale + exp2 conversion into Q
#define QK_SCALE 0.18033688011112042f

__device__ __forceinline__ void gload_lds16(const bf16* g, bf16* l) {
  __builtin_amdgcn_global_load_lds(
      (const __attribute__((address_space(1))) void*)g,
      (__attribute__((address_space(3))) void*)l, 16, 0, 0);
}

__device__ __forceinline__ unsigned packbf(float lo, float hi) {
  bf16x2 t;
  t[0] = (bf16)lo;
  t[1] = (bf16)hi;
  return __builtin_bit_cast(unsigned, t);
}

// v_permlane32_swap_b32: new_a[l>=32] = b_old[l-32]; new_b[l<32] = a_old[l+32]
__device__ __forceinline__ void pl32swap(unsigned& a, unsigned& b) {
#if __has_builtin(__builtin_amdgcn_permlane32_swap)
  auto r = __builtin_amdgcn_permlane32_swap((int)a, (int)b, false, false);
  a = (unsigned)r[0];
  b = (unsigned)r[1];
#else
  asm volatile("v_permlane32_swap_b32 %0, %1" : "+v"(a), "+v"(b));
#endif
}

// ---------------- fused fp32 -> bf16 convert for all 7 tensors ----------------
// outputs land consecutively at d_ws: q,k,v (NQKV each), Wq,Wk,Wv,Wo (NW each)
__global__ __launch_bounds__(256) void cvt_all(
    const float* __restrict__ q, const float* __restrict__ k, const float* __restrict__ v,
    const float* __restrict__ Wq, const float* __restrict__ Wk, const float* __restrict__ Wv,
    const float* __restrict__ Wo, bf16* __restrict__ out) {
  const size_t i = ((size_t)blockIdx.x * 256 + threadIdx.x) * 8;
  const float* src;
  size_t off;
  if (i < (size_t)NQKV) { src = q; off = i; }
  else if (i < 2ull * NQKV) { src = k; off = i - NQKV; }
  else if (i < 3ull * NQKV) { src = v; off = i - 2ull * NQKV; }
  else {
    const size_t j = i - 3ull * NQKV;
    if (j < (size_t)NW) { src = Wq; off = j; }
    else if (j < 2ull * NW) { src = Wk; off = j - NW; }
    else if (j < 3ull * NW) { src = Wv; off = j - 2ull * NW; }
    else { src = Wo; off = j - 3ull * NW; }
  }
  const float4 a = *(const float4*)(src + off);
  const float4 b = *(const float4*)(src + off + 4);
  bf16x8 o;
  o[0] = (bf16)a.x; o[1] = (bf16)a.y; o[2] = (bf16)a.z; o[3] = (bf16)a.w;
  o[4] = (bf16)b.x; o[5] = (bf16)b.y; o[6] = (bf16)b.z; o[7] = (bf16)b.w;
  *(bf16x8*)(out + i) = o;
}

// ---------------- GEMM: Y[m,n] = sum_k A[m,k] * W[n,k] + bias[n] ----------------
// MODE 2: out fp32, row-major [M,N]   (final projection)
// MODE 3: fused QKV. N=3072; segment seg=n0>>10 selects {A-source, bias, scale,
//         output layout}: seg0 Q head-major*QK_SCALE, seg1 K head-major,
//         seg2 V per-head transposed [B,H,hd,S]. A/W/Out bases are consecutive
//         per-segment buffers.
template <int MODE>
__global__ __launch_bounds__(256, 2) void gemm_bt(
    const bf16* __restrict__ A, const bf16* __restrict__ W,
    const float* __restrict__ bias0, const float* __restrict__ bias1,
    const float* __restrict__ bias2, void* __restrict__ Out,
    int M, int N, int K, float scale) {
  __shared__ __align__(16) bf16 Asl[128 * 64];
  __shared__ __align__(16) bf16 Bsl[128 * 64];
  const int tid = threadIdx.x;
  const int lane = tid & 63, w = tid >> 6;
  const int wr = w >> 1, wc = w & 1;
  const int r16 = lane & 15, grp = lane >> 4;
  const int m0 = blockIdx.y * 128, n0 = blockIdx.x * 128;
  const int seg = n0 >> 10;
  const bf16* Ab = (MODE == 3) ? A + (size_t)seg * NQKV : A;

  f32x4 acc[4][4] = {};

  const int nk = K >> 6;
  for (int t = 0; t < nk; ++t) {
    const int k0 = t << 6;
    __syncthreads();
#pragma unroll
    for (int j = 0; j < 4; ++j) {
      const int lin = j * 256 + tid;
      const int rr = lin >> 3;
      const int cc = (lin & 7) * 8;
      gload_lds16(&Ab[(size_t)(m0 + rr) * K + k0 + cc], &Asl[lin * 8]);
      gload_lds16(&W[(size_t)(n0 + rr) * K + k0 + cc], &Bsl[lin * 8]);
    }
    __syncthreads();
#pragma unroll
    for (int kk = 0; kk < 2; ++kk) {
      bf16x8 af[4], bfr[4];
#pragma unroll
      for (int m = 0; m < 4; ++m)
        af[m] = *(const bf16x8*)&Asl[(wr * 64 + m * 16 + r16) * 64 + kk * 32 + grp * 8];
#pragma unroll
      for (int n = 0; n < 4; ++n)
        bfr[n] = *(const bf16x8*)&Bsl[(wc * 64 + n * 16 + r16) * 64 + kk * 32 + grp * 8];
#pragma unroll
      for (int m = 0; m < 4; ++m)
#pragma unroll
        for (int n = 0; n < 4; ++n)
          acc[m][n] = __builtin_amdgcn_mfma_f32_16x16x32_bf16(af[m], bfr[n], acc[m][n], 0, 0, 0);
    }
  }

  const float* bp = (MODE == 3) ? (seg == 0 ? bias0 : (seg == 1 ? bias1 : bias2)) : bias0;
  const float sc = (MODE == 3) ? (seg == 0 ? scale : 1.0f) : scale;
#pragma unroll
  for (int m = 0; m < 4; ++m) {
#pragma unroll
    for (int n = 0; n < 4; ++n) {
#pragma unroll
      for (int r = 0; r < 4; ++r) {
        const int row = m0 + wr * 64 + m * 16 + grp * 4 + r;
        const int col = n0 + wc * 64 + n * 16 + r16;
        const int cs = col & 1023;
        const float v = (acc[m][n][r] + bp[cs]) * sc;
        if (MODE == 3) {
          const int b = row >> 11, s = row & 2047, h = cs >> 6, d = cs & 63;
          bf16* base = (bf16*)Out + (size_t)seg * NQKV;
          if (seg < 2)
            base[((size_t)(b * NH + h) * S_LEN + s) * HD + d] = (bf16)v;
          else
            base[((size_t)(b * NH + h) * HD + d) * S_LEN + s] = (bf16)v;
        } else {
          ((float*)Out)[(size_t)row * N + col] = v;
        }
      }
    }
  }
}

// ---------------- causal flash attention, swapped-operand 32x32 ----------------
// 1 wave (64 threads) per block, 32 q-rows per wave; 2048 blocks, heavy-first.
// QK^T swapped: mfma(A=K, B=Q) -> scores col = q = lane&31 (lane-local softmax).
// PV swapped:   mfma(A=Vt, B=P) -> O col = q (lane-local rescale).
// K-frags double-buffered in registers (explicit ping-pong, no runtime idx).
__global__ __launch_bounds__(64, 2) void attn_fwd3(
    const bf16* __restrict__ Qh, const bf16* __restrict__ Kh,
    const bf16* __restrict__ Vt, bf16* __restrict__ AO) {
  const int lane = threadIdx.x;
  const int q31 = lane & 31, h = lane >> 5;

  const int bid = blockIdx.x;            // 0..2047
  const int xcd = bid & 7;
  const int within = bid >> 3;           // 0..255
  const int bh = xcd * 4 + (within >> 6);   // 4 heads per XCD
  const int c = 63 - (within & 63);      // q-chunk (32 rows), heavy first
  const int q0 = c * 32;
  const int nt = (c >> 1) + 1;           // K-tiles of 64

  const bf16* Qb = Qh + (size_t)bh * S_LEN * HD;
  const bf16* Kb = Kh + (size_t)bh * S_LEN * HD;
  const bf16* Vb = Vt + (size_t)bh * HD * S_LEN;
  const int qg = q0 + q31;

  bf16x8 qf[4];
#pragma unroll
  for (int ks = 0; ks < 4; ++ks)
    qf[ks] = *(const bf16x8*)&Qb[(size_t)qg * HD + ks * 16 + 8 * h];

  f32x16 accO[2] = {};
  float m = -1e30f, l = 0.f;

  bf16x8 kfA[8], kfB[8];
#pragma unroll
  for (int ks = 0; ks < 4; ++ks) {
    kfA[ks]     = *(const bf16x8*)&Kb[(size_t)q31 * HD + ks * 16 + 8 * h];
    kfA[4 + ks] = *(const bf16x8*)&Kb[(size_t)(32 + q31) * HD + ks * 16 + 8 * h];
  }

  auto step = [&](int kt, bf16x8 (&kc)[8], bf16x8 (&kn)[8], bool pf) {
    const int k0 = kt << 6;
    const bool diag = (kt == nt - 1);
    const bool skip1 = diag && (k0 + 32 > q0 + 31);  // upper half fully masked

    // prefetch next tile's K (clamped; wave-uniform predicate)
    if (pf) {
      const int kp = (kt + 1 < nt ? kt + 1 : kt) << 6;
#pragma unroll
      for (int ks = 0; ks < 4; ++ks) {
        kn[ks]     = *(const bf16x8*)&Kb[(size_t)(kp + q31) * HD + ks * 16 + 8 * h];
        kn[4 + ks] = *(const bf16x8*)&Kb[(size_t)(kp + 32 + q31) * HD + ks * 16 + 8 * h];
      }
    }
    // V loads for THIS tile, issued before QK so softmax hides their latency
    bf16x8 vf[8];
#pragma unroll
    for (int ks = 0; ks < 4; ++ks)
#pragma unroll
      for (int db = 0; db < 2; ++db)
        vf[ks * 2 + db] =
            *(const bf16x8*)&Vb[(size_t)(db * 32 + q31) * S_LEN + k0 + ks * 16 + 8 * h];

    // ---- QK^T ----
    f32x16 p0 = {}, p1 = {};
#pragma unroll
    for (int ks = 0; ks < 4; ++ks)
      p0 = __builtin_amdgcn_mfma_f32_32x32x16_bf16(kc[ks], qf[ks], p0, 0, 0, 0);
    if (!skip1) {
#pragma unroll
      for (int ks = 0; ks < 4; ++ks)
        p1 = __builtin_amdgcn_mfma_f32_32x32x16_bf16(kc[4 + ks], qf[ks], p1, 0, 0, 0);
    } else {
#pragma unroll
      for (int r = 0; r < 16; ++r) p1[r] = -1e30f;
    }
    // ---- causal mask (diagonal tile); key row = (r&3)+8*(r>>2)+4h ----
    if (diag) {
#pragma unroll
      for (int r = 0; r < 16; ++r) {
        const int key = k0 + (r & 3) + 8 * (r >> 2) + 4 * h;
        if (key > qg) p0[r] = -1e30f;
        if (!skip1 && key + 32 > qg) p1[r] = -1e30f;
      }
    }
    // ---- softmax: tree max ----
    float t[16];
#pragma unroll
    for (int r = 0; r < 16; ++r) t[r] = fmaxf(p0[r], p1[r]);
#pragma unroll
    for (int s = 8; s >= 1; s >>= 1)
#pragma unroll
      for (int r = 0; r < s; ++r) t[r] = fmaxf(t[r], t[r + s]);
    const float mt = fmaxf(t[0], __shfl_xor(t[0], 32));
    const float mn = fmaxf(m, mt);
    const float alpha = exp2f(m - mn);
    m = mn;
    // ---- exp + tree sum ----
    float sm[16];
#pragma unroll
    for (int r = 0; r < 16; ++r) {
      p0[r] = exp2f(p0[r] - mn);
      p1[r] = exp2f(p1[r] - mn);
      sm[r] = p0[r] + p1[r];
    }
#pragma unroll
    for (int s = 8; s >= 1; s >>= 1)
#pragma unroll
      for (int r = 0; r < s; ++r) sm[r] += sm[r + s];
    const float sum = sm[0] + __shfl_xor(sm[0], 32);
    l = l * alpha + sum;
#pragma unroll
    for (int r = 0; r < 16; ++r) { accO[0][r] *= alpha; accO[1][r] *= alpha; }

    // ---- pack P -> PV B-frags via permlane32_swap ----
    unsigned pw[4][4];
#define PACK_HALF(P, o0, o1)                                                   \
  {                                                                            \
    unsigned wv[8];                                                            \
    _Pragma("unroll") for (int mm = 0; mm < 8; ++mm)                           \
        wv[mm] = packbf(P[2 * mm], P[2 * mm + 1]);                             \
    pl32swap(wv[0], wv[2]);                                                    \
    pl32swap(wv[1], wv[3]);                                                    \
    pl32swap(wv[4], wv[6]);                                                    \
    pl32swap(wv[5], wv[7]);                                                    \
    pw[o0][0] = wv[0]; pw[o0][1] = wv[1]; pw[o0][2] = wv[2]; pw[o0][3] = wv[3];\
    pw[o1][0] = wv[4]; pw[o1][1] = wv[5]; pw[o1][2] = wv[6]; pw[o1][3] = wv[7];\
  }
    PACK_HALF(p0, 0, 1)
    if (!skip1) PACK_HALF(p1, 2, 3)
#undef PACK_HALF

    // ---- PV ----
#define PV_STEP(ks)                                                            \
  {                                                                            \
    u32x4 pu = {pw[ks][0], pw[ks][1], pw[ks][2], pw[ks][3]};                   \
    const bf16x8 pf_ = __builtin_bit_cast(bf16x8, pu);                         \
    accO[0] = __builtin_amdgcn_mfma_f32_32x32x16_bf16(vf[ks * 2 + 0], pf_,     \
                                                      accO[0], 0, 0, 0);       \
    accO[1] = __builtin_amdgcn_mfma_f32_32x32x16_bf16(vf[ks * 2 + 1], pf_,     \
                                                      accO[1], 0, 0, 0);       \
  }
    PV_STEP(0)
    PV_STEP(1)
    if (!skip1) { PV_STEP(2) PV_STEP(3) }
#undef PV_STEP
  };

  int kt = 0;
  while (kt + 2 <= nt) {
    step(kt, kfA, kfB, true);
    step(kt + 1, kfB, kfA, true);
    kt += 2;
  }
  if (kt < nt) step(kt, kfA, kfB, false);

  // ---- store: O row = d = (r&3)+8*(r>>2)+4h+32db, col = q = lane&31 ----
  const float ro = 1.0f / l;
  const int b = bh >> 4, hh = bh & 15;
  bf16* orow = AO + ((size_t)(b * S_LEN + qg)) * DM + hh * HD;
#pragma unroll
  for (int db = 0; db < 2; ++db) {
#pragma unroll
    for (int mm = 0; mm < 4; ++mm) {
      bf16x4 ov;
#pragma unroll
      for (int t = 0; t < 4; ++t) ov[t] = (bf16)(accO[db][4 * mm + t] * ro);
      *(bf16x4*)&orow[db * 32 + 8 * mm + 4 * h] = ov;
    }
  }
}

// ---------------- launch ----------------
extern "C" void kernel_launch(void* const* d_in, const int* in_sizes, int n_in,
                              void* d_out, int out_size, void* d_ws, size_t ws_size,
                              hipStream_t stream) {
  const float* q  = (const float*)d_in[0];
  const float* k  = (const float*)d_in[1];
  const float* v  = (const float*)d_in[2];
  const float* Wq = (const float*)d_in[3];
  const float* bq = (const float*)d_in[4];
  const float* Wk = (const float*)d_in[5];
  const float* bk = (const float*)d_in[6];
  const float* Wv = (const float*)d_in[7];
  const float* bv = (const float*)d_in[8];
  const float* Wo = (const float*)d_in[9];
  const float* bo = (const float*)d_in[10];

  const int NTOK = 2 * S_LEN;          // 4096

  bf16* qb  = (bf16*)d_ws;             // q,k,v bf16: 3 * NQKV (consecutive)
  bf16* Wqb = qb + 3 * (size_t)NQKV;   // Wq,Wk,Wv,Wo bf16: 4 * NW (consecutive)
  bf16* Wob = Wqb + 3 * (size_t)NW;
  bf16* Qh  = Wqb + 4 * (size_t)NW;    // Qh,Kh,Vt bf16: 3 * NQKV (consecutive)
  bf16* Kh  = Qh + (size_t)NQKV;
  bf16* Vt  = Kh + (size_t)NQKV;
  bf16* AO  = Vt + (size_t)NQKV;

  // all converts in one kernel: 3*NQKV + 4*NW elems
  const int cvt_blocks = (3 * NQKV + 4 * NW) / 8 / 256;
  cvt_all<<<cvt_blocks, 256, 0, stream>>>(q, k, v, Wq, Wk, Wv, Wo, qb);

  // fused QKV projection: M=4096, N=3072, K=1024
  gemm_bt<3><<<dim3(3 * DM / 128, NTOK / 128), 256, 0, stream>>>(
      qb, Wqb, bq, bk, bv, Qh, NTOK, 3 * DM, DM, QK_SCALE);

  // attention: 2048 single-wave blocks, heavy-first
  attn_fwd3<<<dim3(2048), 64, 0, stream>>>(Qh, Kh, Vt, AO);

  // output projection -> fp32 d_out
  gemm_bt<2><<<dim3(DM / 128, NTOK / 128), 256, 0, stream>>>(
      AO, Wob, bo, bo, bo, d_out, NTOK, DM, DM, 1.0f);
}

// Round 4
// 144.882 us; speedup vs baseline: 2.4838x; 1.2921x over previous
//
#include <hip/hip_runtime.h>
#include <hip/hip_bf16.h>
#include <cstdint>
#include <cstddef>

typedef __bf16 bf16;
typedef __bf16 bf16x2 __attribute__((ext_vector_type(2)));
typedef __bf16 bf16x4 __attribute__((ext_vector_type(4)));
typedef __bf16 bf16x8 __attribute__((ext_vector_type(8)));
typedef float f32x4 __attribute__((ext_vector_type(4)));
typedef float f32x16 __attribute__((ext_vector_type(16)));
typedef unsigned int u32x4 __attribute__((ext_vector_type(4)));

#define S_LEN 2048
#define DM 1024
#define NH 16
#define HD 64
#define NQKV (4096 * 1024)   // tokens * DM
#define NW (1024 * 1024)
// (1/sqrt(64)) * log2(e): fold softmax scale + exp2 conversion into Q
#define QK_SCALE 0.18033688011112042f

__device__ __forceinline__ void gload_lds16(const bf16* g, bf16* l) {
  __builtin_amdgcn_global_load_lds(
      (const __attribute__((address_space(1))) void*)g,
      (__attribute__((address_space(3))) void*)l, 16, 0, 0);
}

__device__ __forceinline__ unsigned packbf(float lo, float hi) {
  bf16x2 t;
  t[0] = (bf16)lo;
  t[1] = (bf16)hi;
  return __builtin_bit_cast(unsigned, t);
}

// v_permlane32_swap_b32: new_a[l>=32] = b_old[l-32]; new_b[l<32] = a_old[l+32]
__device__ __forceinline__ void pl32swap(unsigned& a, unsigned& b) {
#if __has_builtin(__builtin_amdgcn_permlane32_swap)
  auto r = __builtin_amdgcn_permlane32_swap((int)a, (int)b, false, false);
  a = (unsigned)r[0];
  b = (unsigned)r[1];
#else
  asm volatile("v_permlane32_swap_b32 %0, %1" : "+v"(a), "+v"(b));
#endif
}

// ---------------- fused fp32 -> bf16 convert for all 7 tensors ----------------
__global__ __launch_bounds__(256) void cvt_all(
    const float* __restrict__ q, const float* __restrict__ k, const float* __restrict__ v,
    const float* __restrict__ Wq, const float* __restrict__ Wk, const float* __restrict__ Wv,
    const float* __restrict__ Wo, bf16* __restrict__ out) {
  const size_t i = ((size_t)blockIdx.x * 256 + threadIdx.x) * 8;
  const float* src;
  size_t off;
  if (i < (size_t)NQKV) { src = q; off = i; }
  else if (i < 2ull * NQKV) { src = k; off = i - NQKV; }
  else if (i < 3ull * NQKV) { src = v; off = i - 2ull * NQKV; }
  else {
    const size_t j = i - 3ull * NQKV;
    if (j < (size_t)NW) { src = Wq; off = j; }
    else if (j < 2ull * NW) { src = Wk; off = j - NW; }
    else if (j < 3ull * NW) { src = Wv; off = j - 2ull * NW; }
    else { src = Wo; off = j - 3ull * NW; }
  }
  const float4 a = *(const float4*)(src + off);
  const float4 b = *(const float4*)(src + off + 4);
  bf16x8 o;
  o[0] = (bf16)a.x; o[1] = (bf16)a.y; o[2] = (bf16)a.z; o[3] = (bf16)a.w;
  o[4] = (bf16)b.x; o[5] = (bf16)b.y; o[6] = (bf16)b.z; o[7] = (bf16)b.w;
  *(bf16x8*)(out + i) = o;
}

// ---------------- GEMM: Y[m,n] = sum_k A[m,k] * W[n,k] + bias[n] ----------------
// MODE 2: out fp32, row-major [M,N]   (final projection)
// MODE 3: fused QKV; seg = n0>>10: seg0 Q head-major*QK_SCALE, seg1 K head-major,
//         seg2 V per-head transposed [B,H,hd,S].
template <int MODE>
__global__ __launch_bounds__(256, 2) void gemm_bt(
    const bf16* __restrict__ A, const bf16* __restrict__ W,
    const float* __restrict__ bias0, const float* __restrict__ bias1,
    const float* __restrict__ bias2, void* __restrict__ Out,
    int M, int N, int K, float scale) {
  __shared__ __align__(16) bf16 Asl[128 * 64];
  __shared__ __align__(16) bf16 Bsl[128 * 64];
  const int tid = threadIdx.x;
  const int lane = tid & 63, w = tid >> 6;
  const int wr = w >> 1, wc = w & 1;
  const int r16 = lane & 15, grp = lane >> 4;
  const int m0 = blockIdx.y * 128, n0 = blockIdx.x * 128;
  const int seg = n0 >> 10;
  const bf16* Ab = (MODE == 3) ? A + (size_t)seg * NQKV : A;

  f32x4 acc[4][4] = {};

  const int nk = K >> 6;
  for (int t = 0; t < nk; ++t) {
    const int k0 = t << 6;
    __syncthreads();
#pragma unroll
    for (int j = 0; j < 4; ++j) {
      const int lin = j * 256 + tid;
      const int rr = lin >> 3;
      const int cc = (lin & 7) * 8;
      gload_lds16(&Ab[(size_t)(m0 + rr) * K + k0 + cc], &Asl[lin * 8]);
      gload_lds16(&W[(size_t)(n0 + rr) * K + k0 + cc], &Bsl[lin * 8]);
    }
    __syncthreads();
#pragma unroll
    for (int kk = 0; kk < 2; ++kk) {
      bf16x8 af[4], bfr[4];
#pragma unroll
      for (int m = 0; m < 4; ++m)
        af[m] = *(const bf16x8*)&Asl[(wr * 64 + m * 16 + r16) * 64 + kk * 32 + grp * 8];
#pragma unroll
      for (int n = 0; n < 4; ++n)
        bfr[n] = *(const bf16x8*)&Bsl[(wc * 64 + n * 16 + r16) * 64 + kk * 32 + grp * 8];
#pragma unroll
      for (int m = 0; m < 4; ++m)
#pragma unroll
        for (int n = 0; n < 4; ++n)
          acc[m][n] = __builtin_amdgcn_mfma_f32_16x16x32_bf16(af[m], bfr[n], acc[m][n], 0, 0, 0);
    }
  }

  const float* bp = (MODE == 3) ? (seg == 0 ? bias0 : (seg == 1 ? bias1 : bias2)) : bias0;
  const float sc = (MODE == 3) ? (seg == 0 ? scale : 1.0f) : scale;
#pragma unroll
  for (int m = 0; m < 4; ++m) {
#pragma unroll
    for (int n = 0; n < 4; ++n) {
#pragma unroll
      for (int r = 0; r < 4; ++r) {
        const int row = m0 + wr * 64 + m * 16 + grp * 4 + r;
        const int col = n0 + wc * 64 + n * 16 + r16;
        const int cs = col & 1023;
        const float v = (acc[m][n][r] + bp[cs]) * sc;
        if (MODE == 3) {
          const int b = row >> 11, s = row & 2047, h = cs >> 6, d = cs & 63;
          bf16* base = (bf16*)Out + (size_t)seg * NQKV;
          if (seg < 2)
            base[((size_t)(b * NH + h) * S_LEN + s) * HD + d] = (bf16)v;
          else
            base[((size_t)(b * NH + h) * HD + d) * S_LEN + s] = (bf16)v;
        } else {
          ((float*)Out)[(size_t)row * N + col] = v;
        }
      }
    }
  }
}

// ---------------- causal flash attention, LDS-staged (T2+T3-lite) ----------------
// Block = 4 waves = one (bh, 128 q-rows). Wave w: 32 q-rows at q0+32w.
// K-tile [64 keys][64 d] and V-tile [64 d][64 keys] staged in LDS per block via
// global_load_lds, double-buffered, XOR-swizzled (colbyte ^= (row&7)<<4; applied
// on global SOURCE at stage and on ds_read address -- rule #21).
// QK^T swapped: mfma(A=K, B=Q) -> scores col = q = lane&31 (lane-local softmax).
// PV swapped:   mfma(A=Vt, B=P) -> O col = q (lane-local rescale).
__global__ __launch_bounds__(256, 2) void attn_fwd4(
    const bf16* __restrict__ Qh, const bf16* __restrict__ Kh,
    const bf16* __restrict__ Vt, bf16* __restrict__ AO) {
  __shared__ __align__(16) bf16 Kl[2][64 * 64];
  __shared__ __align__(16) bf16 Vl[2][64 * 64];

  const int tid = threadIdx.x;
  const int lane = tid & 63, w = tid >> 6;
  const int q31 = lane & 31, h = lane >> 5;

  // 8 XCDs x 4 heads; per XCD: heads 0-1 heavy-first, heads 2-3 light-first
  // so the two co-resident blocks per CU sum to ~constant work.
  const int bid = blockIdx.x;            // 0..511
  const int xcd = bid & 7;
  const int within = bid >> 3;           // 0..63
  const int bh = xcd * 4 + (within >> 4);
  const int cc = (within < 32) ? 15 - (within & 15) : (within & 15);
  const int q0 = cc * 128;
  const int nt = 2 * cc + 2;             // block K-tiles of 64
  const int q0w = q0 + 32 * w;
  const int nt_w = (q0w >> 6) + 1;       // this wave's live tiles
  const int qg = q0w + q31;

  const bf16* Qb = Qh + (size_t)bh * S_LEN * HD;
  const bf16* Kb = Kh + (size_t)bh * S_LEN * HD;
  const bf16* Vb = Vt + (size_t)bh * HD * S_LEN;

  // per-lane staging offsets (2 issues x 256 threads = 512 lane-writes of 16B)
  // lin -> LDS row = lin>>3, colbyte = (lin&7)*16; source pre-swizzled.
  int stK[2], stV[2], stL[2];
#pragma unroll
  for (int i = 0; i < 2; ++i) {
    const int lin = i * 256 + tid;
    const int row = lin >> 3;
    const int colb = (lin & 7) * 16;
    const int scol = colb ^ ((row & 7) << 4);
    stK[i] = row * HD + (scol >> 1);        // + k0*HD
    stV[i] = row * S_LEN + (scol >> 1);     // + k0
    stL[i] = lin * 8;
  }

  // Q B-frags: col = q = lane&31, k = ks*16 + 8h + i
  bf16x8 qf[4];
#pragma unroll
  for (int ks = 0; ks < 4; ++ks)
    qf[ks] = *(const bf16x8*)&Qb[(size_t)qg * HD + ks * 16 + 8 * h];

  f32x16 accO[2] = {};
  float m = -1e30f, l = 0.f;

  const int swz = (q31 & 7) << 4;         // read-side XOR (row&7 == q31&7 for all our rows)

  // prologue: stage tile 0 into buffer 0
#pragma unroll
  for (int i = 0; i < 2; ++i) {
    gload_lds16(&Kb[stK[i]], &Kl[0][stL[i]]);
    gload_lds16(&Vb[stV[i]], &Vl[0][stL[i]]);
  }
  __syncthreads();

  int cur = 0;
  for (int kt = 0; kt < nt; ++kt) {
    const int k0 = kt << 6;
    // stage next tile into the other buffer (readers of it finished last iter)
    if (kt + 1 < nt) {
      const int kn = (kt + 1) << 6;
      bf16* kd = Kl[cur ^ 1];
      bf16* vd = Vl[cur ^ 1];
#pragma unroll
      for (int i = 0; i < 2; ++i) {
        gload_lds16(&Kb[(size_t)kn * HD + stK[i]], &kd[stL[i]]);
        gload_lds16(&Vb[kn + stV[i]], &vd[stL[i]]);
      }
    }

    if (kt < nt_w) {
      const bf16* KlC = Kl[cur];
      const bf16* VlC = Vl[cur];
      const bool diag = (kt == nt_w - 1);
      const bool skip1 = diag && (k0 + 32 > q0w + 31);

      // K A-frags from LDS (swizzled read)
      bf16x8 kf[8];
#pragma unroll
      for (int ks = 0; ks < 4; ++ks) {
        const int c = (32 * ks + 16 * h) ^ swz;
        kf[ks]     = *(const bf16x8*)((const char*)KlC + q31 * 128 + c);
        kf[4 + ks] = *(const bf16x8*)((const char*)KlC + (32 + q31) * 128 + c);
      }

      // ---- QK^T ----
      f32x16 p0 = {}, p1 = {};
#pragma unroll
      for (int ks = 0; ks < 4; ++ks)
        p0 = __builtin_amdgcn_mfma_f32_32x32x16_bf16(kf[ks], qf[ks], p0, 0, 0, 0);
      if (!skip1) {
#pragma unroll
        for (int ks = 0; ks < 4; ++ks)
          p1 = __builtin_amdgcn_mfma_f32_32x32x16_bf16(kf[4 + ks], qf[ks], p1, 0, 0, 0);
      } else {
#pragma unroll
        for (int r = 0; r < 16; ++r) p1[r] = -1e30f;
      }

      // V A-frags for ks 0..1 issued early (latency hides under softmax)
      bf16x8 vf01[4];
#pragma unroll
      for (int ks = 0; ks < 2; ++ks)
#pragma unroll
        for (int db = 0; db < 2; ++db) {
          const int c = (32 * ks + 16 * h) ^ swz;
          vf01[ks * 2 + db] =
              *(const bf16x8*)((const char*)VlC + (db * 32 + q31) * 128 + c);
        }

      // ---- causal mask (diagonal tile); key row = (r&3)+8*(r>>2)+4h ----
      if (diag) {
#pragma unroll
        for (int r = 0; r < 16; ++r) {
          const int key = k0 + (r & 3) + 8 * (r >> 2) + 4 * h;
          if (key > qg) p0[r] = -1e30f;
          if (!skip1 && key + 32 > qg) p1[r] = -1e30f;
        }
      }
      // ---- softmax: tree max ----
      float t[16];
#pragma unroll
      for (int r = 0; r < 16; ++r) t[r] = fmaxf(p0[r], p1[r]);
#pragma unroll
      for (int s = 8; s >= 1; s >>= 1)
#pragma unroll
        for (int r = 0; r < s; ++r) t[r] = fmaxf(t[r], t[r + s]);
      const float mt = fmaxf(t[0], __shfl_xor(t[0], 32));
      const float mn = fmaxf(m, mt);
      const float alpha = exp2f(m - mn);
      m = mn;
      // ---- exp + tree sum ----
      float sm[16];
#pragma unroll
      for (int r = 0; r < 16; ++r) {
        p0[r] = exp2f(p0[r] - mn);
        p1[r] = exp2f(p1[r] - mn);
        sm[r] = p0[r] + p1[r];
      }
#pragma unroll
      for (int s = 8; s >= 1; s >>= 1)
#pragma unroll
        for (int r = 0; r < s; ++r) sm[r] += sm[r + s];
      const float sum = sm[0] + __shfl_xor(sm[0], 32);
      l = l * alpha + sum;
#pragma unroll
      for (int r = 0; r < 16; ++r) { accO[0][r] *= alpha; accO[1][r] *= alpha; }

      // ---- pack P -> PV B-frags via permlane32_swap ----
      unsigned pw[4][4];
#define PACK_HALF(P, o0, o1)                                                   \
  {                                                                            \
    unsigned wv[8];                                                            \
    _Pragma("unroll") for (int mm = 0; mm < 8; ++mm)                           \
        wv[mm] = packbf(P[2 * mm], P[2 * mm + 1]);                             \
    pl32swap(wv[0], wv[2]);                                                    \
    pl32swap(wv[1], wv[3]);                                                    \
    pl32swap(wv[4], wv[6]);                                                    \
    pl32swap(wv[5], wv[7]);                                                    \
    pw[o0][0] = wv[0]; pw[o0][1] = wv[1]; pw[o0][2] = wv[2]; pw[o0][3] = wv[3];\
    pw[o1][0] = wv[4]; pw[o1][1] = wv[5]; pw[o1][2] = wv[6]; pw[o1][3] = wv[7];\
  }
      PACK_HALF(p0, 0, 1)
      if (!skip1) PACK_HALF(p1, 2, 3)
#undef PACK_HALF

      // V A-frags for ks 2..3 (hide under PV ks 0..1)
      bf16x8 vf23[4];
      if (!skip1) {
#pragma unroll
        for (int ks = 2; ks < 4; ++ks)
#pragma unroll
          for (int db = 0; db < 2; ++db) {
            const int c = (32 * ks + 16 * h) ^ swz;
            vf23[(ks - 2) * 2 + db] =
                *(const bf16x8*)((const char*)VlC + (db * 32 + q31) * 128 + c);
          }
      }

      // ---- PV ----
#define PV_STEP(ks, vfa)                                                       \
  {                                                                            \
    u32x4 pu = {pw[ks][0], pw[ks][1], pw[ks][2], pw[ks][3]};                   \
    const bf16x8 pf_ = __builtin_bit_cast(bf16x8, pu);                         \
    accO[0] = __builtin_amdgcn_mfma_f32_32x32x16_bf16(vfa[(ks & 1) * 2 + 0],   \
                                                      pf_, accO[0], 0, 0, 0);  \
    accO[1] = __builtin_amdgcn_mfma_f32_32x32x16_bf16(vfa[(ks & 1) * 2 + 1],   \
                                                      pf_, accO[1], 0, 0, 0);  \
  }
      PV_STEP(0, vf01)
      PV_STEP(1, vf01)
      if (!skip1) { PV_STEP(2, vf23) PV_STEP(3, vf23) }
#undef PV_STEP
    }

    __syncthreads();  // drains vmcnt (stage kt+1 done) + all reads of buf[cur] retired
    cur ^= 1;
  }

  // ---- store: O row = d = (r&3)+8*(r>>2)+4h+32db, col = q = lane&31 ----
  const float ro = 1.0f / l;
  const int b = bh >> 4, hh = bh & 15;
  bf16* orow = AO + ((size_t)(b * S_LEN + qg)) * DM + hh * HD;
#pragma unroll
  for (int db = 0; db < 2; ++db) {
#pragma unroll
    for (int mm = 0; mm < 4; ++mm) {
      bf16x4 ov;
#pragma unroll
      for (int t = 0; t < 4; ++t) ov[t] = (bf16)(accO[db][4 * mm + t] * ro);
      *(bf16x4*)&orow[db * 32 + 8 * mm + 4 * h] = ov;
    }
  }
}

// ---------------- launch ----------------
extern "C" void kernel_launch(void* const* d_in, const int* in_sizes, int n_in,
                              void* d_out, int out_size, void* d_ws, size_t ws_size,
                              hipStream_t stream) {
  const float* q  = (const float*)d_in[0];
  const float* k  = (const float*)d_in[1];
  const float* v  = (const float*)d_in[2];
  const float* Wq = (const float*)d_in[3];
  const float* bq = (const float*)d_in[4];
  const float* Wk = (const float*)d_in[5];
  const float* bk = (const float*)d_in[6];
  const float* Wv = (const float*)d_in[7];
  const float* bv = (const float*)d_in[8];
  const float* Wo = (const float*)d_in[9];
  const float* bo = (const float*)d_in[10];

  const int NTOK = 2 * S_LEN;          // 4096

  bf16* qb  = (bf16*)d_ws;             // q,k,v bf16: 3 * NQKV (consecutive)
  bf16* Wqb = qb + 3 * (size_t)NQKV;   // Wq,Wk,Wv,Wo bf16: 4 * NW (consecutive)
  bf16* Wob = Wqb + 3 * (size_t)NW;
  bf16* Qh  = Wqb + 4 * (size_t)NW;    // Qh,Kh,Vt bf16: 3 * NQKV (consecutive)
  bf16* Kh  = Qh + (size_t)NQKV;
  bf16* Vt  = Kh + (size_t)NQKV;
  bf16* AO  = Vt + (size_t)NQKV;

  const int cvt_blocks = (3 * NQKV + 4 * NW) / 8 / 256;
  cvt_all<<<cvt_blocks, 256, 0, stream>>>(q, k, v, Wq, Wk, Wv, Wo, qb);

  // fused QKV projection: M=4096, N=3072, K=1024
  gemm_bt<3><<<dim3(3 * DM / 128, NTOK / 128), 256, 0, stream>>>(
      qb, Wqb, bq, bk, bv, Qh, NTOK, 3 * DM, DM, QK_SCALE);

  // attention: 512 blocks x 256 threads, LDS-staged, balanced pairing
  attn_fwd4<<<dim3(512), 256, 0, stream>>>(Qh, Kh, Vt, AO);

  // output projection -> fp32 d_out
  gemm_bt<2><<<dim3(DM / 128, NTOK / 128), 256, 0, stream>>>(
      AO, Wob, bo, bo, bo, d_out, NTOK, DM, DM, 1.0f);
}

// Round 5
// 135.679 us; speedup vs baseline: 2.6523x; 1.0678x over previous
//
#include <hip/hip_runtime.h>
#include <hip/hip_bf16.h>
#include <cstdint>
#include <cstddef>

typedef __bf16 bf16;
typedef __bf16 bf16x2 __attribute__((ext_vector_type(2)));
typedef __bf16 bf16x4 __attribute__((ext_vector_type(4)));
typedef __bf16 bf16x8 __attribute__((ext_vector_type(8)));
typedef float f32x4 __attribute__((ext_vector_type(4)));
typedef float f32x16 __attribute__((ext_vector_type(16)));
typedef unsigned int u32x4 __attribute__((ext_vector_type(4)));

#define S_LEN 2048
#define DM 1024
#define NH 16
#define HD 64
#define NQKV (4096 * 1024)   // tokens * DM
#define NW (1024 * 1024)
// (1/sqrt(64)) * log2(e): fold softmax scale + exp2 conversion into Q
#define QK_SCALE 0.18033688011112042f

__device__ __forceinline__ void gload_lds16(const bf16* g, bf16* l) {
  __builtin_amdgcn_global_load_lds(
      (const __attribute__((address_space(1))) void*)g,
      (__attribute__((address_space(3))) void*)l, 16, 0, 0);
}

__device__ __forceinline__ unsigned packbf(float lo, float hi) {
  bf16x2 t;
  t[0] = (bf16)lo;
  t[1] = (bf16)hi;
  return __builtin_bit_cast(unsigned, t);
}

// v_permlane32_swap_b32: new_a[l>=32] = b_old[l-32]; new_b[l<32] = a_old[l+32]
__device__ __forceinline__ void pl32swap(unsigned& a, unsigned& b) {
#if __has_builtin(__builtin_amdgcn_permlane32_swap)
  auto r = __builtin_amdgcn_permlane32_swap((int)a, (int)b, false, false);
  a = (unsigned)r[0];
  b = (unsigned)r[1];
#else
  asm volatile("v_permlane32_swap_b32 %0, %1" : "+v"(a), "+v"(b));
#endif
}

// ---------------- fused fp32 -> bf16 convert for all 7 tensors ----------------
__global__ __launch_bounds__(256) void cvt_all(
    const float* __restrict__ q, const float* __restrict__ k, const float* __restrict__ v,
    const float* __restrict__ Wq, const float* __restrict__ Wk, const float* __restrict__ Wv,
    const float* __restrict__ Wo, bf16* __restrict__ out) {
  const size_t i = ((size_t)blockIdx.x * 256 + threadIdx.x) * 8;
  const float* src;
  size_t off;
  if (i < (size_t)NQKV) { src = q; off = i; }
  else if (i < 2ull * NQKV) { src = k; off = i - NQKV; }
  else if (i < 3ull * NQKV) { src = v; off = i - 2ull * NQKV; }
  else {
    const size_t j = i - 3ull * NQKV;
    if (j < (size_t)NW) { src = Wq; off = j; }
    else if (j < 2ull * NW) { src = Wk; off = j - NW; }
    else if (j < 3ull * NW) { src = Wv; off = j - 2ull * NW; }
    else { src = Wo; off = j - 3ull * NW; }
  }
  const float4 a = *(const float4*)(src + off);
  const float4 b = *(const float4*)(src + off + 4);
  bf16x8 o;
  o[0] = (bf16)a.x; o[1] = (bf16)a.y; o[2] = (bf16)a.z; o[3] = (bf16)a.w;
  o[4] = (bf16)b.x; o[5] = (bf16)b.y; o[6] = (bf16)b.z; o[7] = (bf16)b.w;
  *(bf16x8*)(out + i) = o;
}

// ---------------- GEMM: Y[m,n] = sum_k A[m,k] * W[n,k] + bias[n] ----------------
// MODE 2: out fp32, row-major [M,N]   (final projection)
// MODE 3: fused QKV; seg = n0>>10: seg0 Q head-major*QK_SCALE, seg1 K head-major,
//         seg2 V per-head transposed [B,H,hd,S] via LDS-transposed epilogue.
// Both grids have nwg % 8 == 0 -> simple bijective XCD swizzle.
template <int MODE>
__global__ __launch_bounds__(256, 2) void gemm_bt(
    const bf16* __restrict__ A, const bf16* __restrict__ W,
    const float* __restrict__ bias0, const float* __restrict__ bias1,
    const float* __restrict__ bias2, void* __restrict__ Out,
    int M, int N, int K, float scale) {
  __shared__ __align__(16) bf16 sm[2 * 128 * 64];
  bf16* Asl = sm;
  bf16* Bsl = sm + 128 * 64;
  const int tid = threadIdx.x;
  const int lane = tid & 63, w = tid >> 6;
  const int wr = w >> 1, wc = w & 1;
  const int r16 = lane & 15, grp = lane >> 4;

  // XCD swizzle: consecutive blocks within an XCD share A-panels
  int flat = blockIdx.y * gridDim.x + blockIdx.x;
  const int cpx = (gridDim.x * gridDim.y) >> 3;
  flat = (flat & 7) * cpx + (flat >> 3);
  const int m0 = (flat / gridDim.x) * 128;
  const int n0 = (flat % gridDim.x) * 128;

  const int seg = n0 >> 10;
  const bf16* Ab = (MODE == 3) ? A + (size_t)seg * NQKV : A;

  f32x4 acc[4][4] = {};

  const int nk = K >> 6;
  for (int t = 0; t < nk; ++t) {
    const int k0 = t << 6;
    __syncthreads();
#pragma unroll
    for (int j = 0; j < 4; ++j) {
      const int lin = j * 256 + tid;
      const int rr = lin >> 3;
      const int cc = (lin & 7) * 8;
      gload_lds16(&Ab[(size_t)(m0 + rr) * K + k0 + cc], &Asl[lin * 8]);
      gload_lds16(&W[(size_t)(n0 + rr) * K + k0 + cc], &Bsl[lin * 8]);
    }
    __syncthreads();
#pragma unroll
    for (int kk = 0; kk < 2; ++kk) {
      bf16x8 af[4], bfr[4];
#pragma unroll
      for (int m = 0; m < 4; ++m)
        af[m] = *(const bf16x8*)&Asl[(wr * 64 + m * 16 + r16) * 64 + kk * 32 + grp * 8];
#pragma unroll
      for (int n = 0; n < 4; ++n)
        bfr[n] = *(const bf16x8*)&Bsl[(wc * 64 + n * 16 + r16) * 64 + kk * 32 + grp * 8];
#pragma unroll
      for (int m = 0; m < 4; ++m)
#pragma unroll
        for (int n = 0; n < 4; ++n)
          acc[m][n] = __builtin_amdgcn_mfma_f32_16x16x32_bf16(af[m], bfr[n], acc[m][n], 0, 0, 0);
    }
  }

  const float* bp = (MODE == 3) ? (seg == 0 ? bias0 : (seg == 1 ? bias1 : bias2)) : bias0;
  const float sc = (MODE == 3) ? (seg == 0 ? scale : 1.0f) : scale;

  if (MODE == 3 && seg == 2) {
    // ---- V^T epilogue: transpose each wave's 64x64 quadrant via LDS ----
    // T[d_local][s_local], pitch 76 elems (152B: 2-way max on writes+reads).
    __syncthreads();  // all Asl/Bsl readers done
    bf16* T = sm + w * (32 * 76);
    const int b = (m0 + wr * 64) >> 11;
    const int srow0 = (m0 + wr * 64) & 2047;
    bf16* base2 = (bf16*)Out + 2 * (size_t)NQKV;
#pragma unroll
    for (int p = 0; p < 2; ++p) {
#pragma unroll
      for (int nn = 0; nn < 2; ++nn) {
        const int n = 2 * p + nn;
#pragma unroll
        for (int mq = 0; mq < 4; ++mq)
#pragma unroll
          for (int r = 0; r < 4; ++r) {
            const int d_l = nn * 16 + r16;
            const int s_l = mq * 16 + grp * 4 + r;
            const int cs = (n0 + wc * 64 + n * 16 + r16) & 1023;
            T[d_l * 76 + s_l] = (bf16)(acc[mq][n][r] + bp[cs]);
          }
      }
      __syncthreads();
#pragma unroll
      for (int j = 0; j < 4; ++j) {
        const int d_l = j * 8 + (lane >> 3);
        const int scnk = lane & 7;
        const uint2 lo = *(const uint2*)&T[d_l * 76 + scnk * 8];
        const uint2 hi = *(const uint2*)&T[d_l * 76 + scnk * 8 + 4];
        const int cs = (n0 + wc * 64 + p * 32 + d_l) & 1023;
        const int hh = cs >> 6, dd = cs & 63;
        bf16* dst = base2 + ((size_t)(b * NH + hh) * HD + dd) * S_LEN + srow0 + scnk * 8;
        uint4 val; val.x = lo.x; val.y = lo.y; val.z = hi.x; val.w = hi.y;
        *(uint4*)dst = val;
      }
      __syncthreads();
    }
    return;
  }

#pragma unroll
  for (int m = 0; m < 4; ++m) {
#pragma unroll
    for (int n = 0; n < 4; ++n) {
#pragma unroll
      for (int r = 0; r < 4; ++r) {
        const int row = m0 + wr * 64 + m * 16 + grp * 4 + r;
        const int col = n0 + wc * 64 + n * 16 + r16;
        const int cs = col & 1023;
        const float v = (acc[m][n][r] + bp[cs]) * sc;
        if (MODE == 3) {  // seg 0/1: head-major
          const int b = row >> 11, s = row & 2047, h = cs >> 6, d = cs & 63;
          bf16* base = (bf16*)Out + (size_t)seg * NQKV;
          base[((size_t)(b * NH + h) * S_LEN + s) * HD + d] = (bf16)v;
        } else {
          ((float*)Out)[(size_t)row * N + col] = v;
        }
      }
    }
  }
}

// ---------------- causal flash attention, LDS-staged, 2-wave blocks ----------------
// Block = 2 waves = one (bh, 64 q-rows); 1024 blocks, heavy-first, XCD-grouped.
// K-tile [64 k][64 d], V-tile [64 d][64 k] staged via global_load_lds, dbuf,
// XOR-swizzled (src pre-swizzle + XOR'd ds_read). Swapped-operand MFMA:
// QK^T mfma(K,Q), PV mfma(Vt,P) -> softmax state lane-local (col = q = lane&31).
// T13 defer-max (THR=8), T5 setprio around MFMA clusters.
__global__ __launch_bounds__(128, 2) void attn_fwd5(
    const bf16* __restrict__ Qh, const bf16* __restrict__ Kh,
    const bf16* __restrict__ Vt, bf16* __restrict__ AO) {
  __shared__ __align__(16) bf16 Kl[2][64 * 64];
  __shared__ __align__(16) bf16 Vl[2][64 * 64];

  const int tid = threadIdx.x;
  const int lane = tid & 63, w = tid >> 6;
  const int q31 = lane & 31, h = lane >> 5;

  // 1024 blocks: xcd = bid&7 (4 heads per XCD for K/V L2 residency);
  // idx>>2 walks q-chunks heavy-first across the 4 heads.
  const int bid = blockIdx.x;
  const int xcd = bid & 7;
  const int idx = bid >> 3;              // 0..127
  const int cc = 31 - (idx >> 2);        // q-chunk of 64 rows, heavy first
  const int bh = xcd * 4 + (idx & 3);
  const int q0 = cc * 64;
  const int nt = cc + 1;                 // K-tiles of 64 (both waves live in all)
  const int q0w = q0 + 32 * w;
  const int qg = q0w + q31;

  const bf16* Qb = Qh + (size_t)bh * S_LEN * HD;
  const bf16* Kb = Kh + (size_t)bh * S_LEN * HD;
  const bf16* Vb = Vt + (size_t)bh * HD * S_LEN;

  // staging: 1024 x 16B per tile (K 8KB + V 8KB); 128 threads x 4 issues each
  int stK[4], stV[4], stL[4];
#pragma unroll
  for (int i = 0; i < 4; ++i) {
    const int lin = i * 128 + tid;       // 0..511
    const int row = lin >> 3;
    const int colb = (lin & 7) * 16;
    const int scol = colb ^ ((row & 7) << 4);
    stK[i] = row * HD + (scol >> 1);
    stV[i] = row * S_LEN + (scol >> 1);
    stL[i] = lin * 8;
  }

  bf16x8 qf[4];
#pragma unroll
  for (int ks = 0; ks < 4; ++ks)
    qf[ks] = *(const bf16x8*)&Qb[(size_t)qg * HD + ks * 16 + 8 * h];

  f32x16 accO[2] = {};
  float m = -1e30f, l = 0.f;

  const int swz = (q31 & 7) << 4;

  // prologue: stage tile 0 into buffer 0
#pragma unroll
  for (int i = 0; i < 4; ++i) {
    gload_lds16(&Kb[stK[i]], &Kl[0][stL[i]]);
    gload_lds16(&Vb[stV[i]], &Vl[0][stL[i]]);
  }
  __syncthreads();

  int cur = 0;
  for (int kt = 0; kt < nt; ++kt) {
    const int k0 = kt << 6;
    if (kt + 1 < nt) {
      const int kn = (kt + 1) << 6;
      bf16* kd = Kl[cur ^ 1];
      bf16* vd = Vl[cur ^ 1];
#pragma unroll
      for (int i = 0; i < 4; ++i) {
        gload_lds16(&Kb[(size_t)kn * HD + stK[i]], &kd[stL[i]]);
        gload_lds16(&Vb[kn + stV[i]], &vd[stL[i]]);
      }
    }

    const bf16* KlC = Kl[cur];
    const bf16* VlC = Vl[cur];
    const bool diag = (kt == nt - 1);
    const bool skip1 = diag && (w == 0);  // upper half fully masked for wave 0

    bf16x8 kf[8];
#pragma unroll
    for (int ks = 0; ks < 4; ++ks) {
      const int c = (32 * ks + 16 * h) ^ swz;
      kf[ks]     = *(const bf16x8*)((const char*)KlC + q31 * 128 + c);
      kf[4 + ks] = *(const bf16x8*)((const char*)KlC + (32 + q31) * 128 + c);
    }

    // ---- QK^T ----
    f32x16 p0 = {}, p1 = {};
    __builtin_amdgcn_s_setprio(1);
#pragma unroll
    for (int ks = 0; ks < 4; ++ks)
      p0 = __builtin_amdgcn_mfma_f32_32x32x16_bf16(kf[ks], qf[ks], p0, 0, 0, 0);
    __builtin_amdgcn_s_setprio(0);
    if (!skip1) {
      __builtin_amdgcn_s_setprio(1);
#pragma unroll
      for (int ks = 0; ks < 4; ++ks)
        p1 = __builtin_amdgcn_mfma_f32_32x32x16_bf16(kf[4 + ks], qf[ks], p1, 0, 0, 0);
      __builtin_amdgcn_s_setprio(0);
    } else {
#pragma unroll
      for (int r = 0; r < 16; ++r) p1[r] = -1e30f;
    }

    // V A-frags ks 0..1 issued early (hide LDS latency under softmax)
    bf16x8 vf01[4];
#pragma unroll
    for (int ks = 0; ks < 2; ++ks)
#pragma unroll
      for (int db = 0; db < 2; ++db) {
        const int c = (32 * ks + 16 * h) ^ swz;
        vf01[ks * 2 + db] =
            *(const bf16x8*)((const char*)VlC + (db * 32 + q31) * 128 + c);
      }

    // ---- causal mask (diagonal tile); key row = (r&3)+8*(r>>2)+4h ----
    if (diag) {
#pragma unroll
      for (int r = 0; r < 16; ++r) {
        const int key = k0 + (r & 3) + 8 * (r >> 2) + 4 * h;
        if (key > qg) p0[r] = -1e30f;
        if (!skip1 && key + 32 > qg) p1[r] = -1e30f;
      }
    }
    // ---- tree max ----
    float t[16];
#pragma unroll
    for (int r = 0; r < 16; ++r) t[r] = fmaxf(p0[r], p1[r]);
#pragma unroll
    for (int s = 8; s >= 1; s >>= 1)
#pragma unroll
      for (int r = 0; r < s; ++r) t[r] = fmaxf(t[r], t[r + s]);
    const float pmax = fmaxf(t[0], __shfl_xor(t[0], 32));
    // ---- defer-max (T13): rescale only when max grew by > 8 ----
    if (!__all(pmax - m <= 8.0f)) {
      const float mn = fmaxf(m, pmax);
      const float alpha = exp2f(m - mn);
      m = mn;
      l *= alpha;
#pragma unroll
      for (int r = 0; r < 16; ++r) { accO[0][r] *= alpha; accO[1][r] *= alpha; }
    }
    // ---- exp + tree sum ----
    float smv[16];
#pragma unroll
    for (int r = 0; r < 16; ++r) {
      p0[r] = exp2f(p0[r] - m);
      p1[r] = exp2f(p1[r] - m);
      smv[r] = p0[r] + p1[r];
    }
#pragma unroll
    for (int s = 8; s >= 1; s >>= 1)
#pragma unroll
      for (int r = 0; r < s; ++r) smv[r] += smv[r + s];
    l += smv[0] + __shfl_xor(smv[0], 32);

    // ---- pack P -> PV B-frags via permlane32_swap ----
    unsigned pw[4][4];
#define PACK_HALF(P, o0, o1)                                                   \
  {                                                                            \
    unsigned wv[8];                                                            \
    _Pragma("unroll") for (int mm = 0; mm < 8; ++mm)                           \
        wv[mm] = packbf(P[2 * mm], P[2 * mm + 1]);                             \
    pl32swap(wv[0], wv[2]);                                                    \
    pl32swap(wv[1], wv[3]);                                                    \
    pl32swap(wv[4], wv[6]);                                                    \
    pl32swap(wv[5], wv[7]);                                                    \
    pw[o0][0] = wv[0]; pw[o0][1] = wv[1]; pw[o0][2] = wv[2]; pw[o0][3] = wv[3];\
    pw[o1][0] = wv[4]; pw[o1][1] = wv[5]; pw[o1][2] = wv[6]; pw[o1][3] = wv[7];\
  }
    PACK_HALF(p0, 0, 1)
    if (!skip1) PACK_HALF(p1, 2, 3)
#undef PACK_HALF

    bf16x8 vf23[4];
    if (!skip1) {
#pragma unroll
      for (int ks = 2; ks < 4; ++ks)
#pragma unroll
        for (int db = 0; db < 2; ++db) {
          const int c = (32 * ks + 16 * h) ^ swz;
          vf23[(ks - 2) * 2 + db] =
              *(const bf16x8*)((const char*)VlC + (db * 32 + q31) * 128 + c);
        }
    }

    // ---- PV ----
#define PV_STEP(ks, vfa)                                                       \
  {                                                                            \
    u32x4 pu = {pw[ks][0], pw[ks][1], pw[ks][2], pw[ks][3]};                   \
    const bf16x8 pf_ = __builtin_bit_cast(bf16x8, pu);                         \
    accO[0] = __builtin_amdgcn_mfma_f32_32x32x16_bf16(vfa[(ks & 1) * 2 + 0],   \
                                                      pf_, accO[0], 0, 0, 0);  \
    accO[1] = __builtin_amdgcn_mfma_f32_32x32x16_bf16(vfa[(ks & 1) * 2 + 1],   \
                                                      pf_, accO[1], 0, 0, 0);  \
  }
    __builtin_amdgcn_s_setprio(1);
    PV_STEP(0, vf01)
    PV_STEP(1, vf01)
    __builtin_amdgcn_s_setprio(0);
    if (!skip1) {
      __builtin_amdgcn_s_setprio(1);
      PV_STEP(2, vf23)
      PV_STEP(3, vf23)
      __builtin_amdgcn_s_setprio(0);
    }
#undef PV_STEP

    __syncthreads();  // stage kt+1 landed + all reads of buf[cur] retired
    cur ^= 1;
  }

  // ---- store: O row = d = (r&3)+8*(r>>2)+4h+32db, col = q = lane&31 ----
  const float ro = 1.0f / l;
  const int b = bh >> 4, hh = bh & 15;
  bf16* orow = AO + ((size_t)(b * S_LEN + qg)) * DM + hh * HD;
#pragma unroll
  for (int db = 0; db < 2; ++db) {
#pragma unroll
    for (int mm = 0; mm < 4; ++mm) {
      bf16x4 ov;
#pragma unroll
      for (int t = 0; t < 4; ++t) ov[t] = (bf16)(accO[db][4 * mm + t] * ro);
      *(bf16x4*)&orow[db * 32 + 8 * mm + 4 * h] = ov;
    }
  }
}

// ---------------- launch ----------------
extern "C" void kernel_launch(void* const* d_in, const int* in_sizes, int n_in,
                              void* d_out, int out_size, void* d_ws, size_t ws_size,
                              hipStream_t stream) {
  const float* q  = (const float*)d_in[0];
  const float* k  = (const float*)d_in[1];
  const float* v  = (const float*)d_in[2];
  const float* Wq = (const float*)d_in[3];
  const float* bq = (const float*)d_in[4];
  const float* bk = (const float*)d_in[6];
  const float* bv = (const float*)d_in[8];
  const float* Wo = (const float*)d_in[9];
  const float* bo = (const float*)d_in[10];

  const int NTOK = 2 * S_LEN;          // 4096

  bf16* qb  = (bf16*)d_ws;             // q,k,v bf16: 3 * NQKV (consecutive)
  bf16* Wqb = qb + 3 * (size_t)NQKV;   // Wq,Wk,Wv,Wo bf16: 4 * NW (consecutive)
  bf16* Wob = Wqb + 3 * (size_t)NW;
  bf16* Qh  = Wqb + 4 * (size_t)NW;    // Qh,Kh,Vt bf16: 3 * NQKV (consecutive)
  bf16* Kh  = Qh + (size_t)NQKV;
  bf16* Vt  = Kh + (size_t)NQKV;
  bf16* AO  = Vt + (size_t)NQKV;

  const int cvt_blocks = (3 * NQKV + 4 * NW) / 8 / 256;
  cvt_all<<<cvt_blocks, 256, 0, stream>>>(q, k, (const float*)d_in[2],
                                          (const float*)d_in[3], (const float*)d_in[5],
                                          (const float*)d_in[7], Wo, qb);

  // fused QKV projection: M=4096, N=3072, K=1024
  gemm_bt<3><<<dim3(3 * DM / 128, NTOK / 128), 256, 0, stream>>>(
      qb, Wqb, bq, bk, bv, Qh, NTOK, 3 * DM, DM, QK_SCALE);

  // attention: 1024 blocks x 128 threads, heavy-first
  attn_fwd5<<<dim3(1024), 128, 0, stream>>>(Qh, Kh, Vt, AO);

  // output projection -> fp32 d_out
  gemm_bt<2><<<dim3(DM / 128, NTOK / 128), 256, 0, stream>>>(
      AO, Wob, bo, bo, bo, d_out, NTOK, DM, DM, 1.0f);
}

// Round 6
// 133.171 us; speedup vs baseline: 2.7022x; 1.0188x over previous
//
#include <hip/hip_runtime.h>
#include <hip/hip_bf16.h>
#include <cstdint>
#include <cstddef>

typedef __bf16 bf16;
typedef __bf16 bf16x2 __attribute__((ext_vector_type(2)));
typedef __bf16 bf16x4 __attribute__((ext_vector_type(4)));
typedef __bf16 bf16x8 __attribute__((ext_vector_type(8)));
typedef float f32x4 __attribute__((ext_vector_type(4)));
typedef float f32x16 __attribute__((ext_vector_type(16)));
typedef unsigned int u32x4 __attribute__((ext_vector_type(4)));

#define S_LEN 2048
#define DM 1024
#define NH 16
#define HD 64
#define NQKV (4096 * 1024)   // tokens * DM
#define NW (1024 * 1024)
// (1/sqrt(64)) * log2(e): fold softmax scale + exp2 conversion into Q
#define QK_SCALE 0.18033688011112042f

__device__ __forceinline__ void gload_lds16(const bf16* g, bf16* l) {
  __builtin_amdgcn_global_load_lds(
      (const __attribute__((address_space(1))) void*)g,
      (__attribute__((address_space(3))) void*)l, 16, 0, 0);
}

__device__ __forceinline__ unsigned packbf(float lo, float hi) {
  bf16x2 t;
  t[0] = (bf16)lo;
  t[1] = (bf16)hi;
  return __builtin_bit_cast(unsigned, t);
}

// v_permlane32_swap_b32: new_a[l>=32] = b_old[l-32]; new_b[l<32] = a_old[l+32]
__device__ __forceinline__ void pl32swap(unsigned& a, unsigned& b) {
#if __has_builtin(__builtin_amdgcn_permlane32_swap)
  auto r = __builtin_amdgcn_permlane32_swap((int)a, (int)b, false, false);
  a = (unsigned)r[0];
  b = (unsigned)r[1];
#else
  asm volatile("v_permlane32_swap_b32 %0, %1" : "+v"(a), "+v"(b));
#endif
}

// ---------------- fused fp32 -> bf16 convert for all 7 tensors ----------------
__global__ __launch_bounds__(256) void cvt_all(
    const float* __restrict__ q, const float* __restrict__ k, const float* __restrict__ v,
    const float* __restrict__ Wq, const float* __restrict__ Wk, const float* __restrict__ Wv,
    const float* __restrict__ Wo, bf16* __restrict__ out) {
  const size_t i = ((size_t)blockIdx.x * 256 + threadIdx.x) * 8;
  const float* src;
  size_t off;
  if (i < (size_t)NQKV) { src = q; off = i; }
  else if (i < 2ull * NQKV) { src = k; off = i - NQKV; }
  else if (i < 3ull * NQKV) { src = v; off = i - 2ull * NQKV; }
  else {
    const size_t j = i - 3ull * NQKV;
    if (j < (size_t)NW) { src = Wq; off = j; }
    else if (j < 2ull * NW) { src = Wk; off = j - NW; }
    else if (j < 3ull * NW) { src = Wv; off = j - 2ull * NW; }
    else { src = Wo; off = j - 3ull * NW; }
  }
  const float4 a = *(const float4*)(src + off);
  const float4 b = *(const float4*)(src + off + 4);
  bf16x8 o;
  o[0] = (bf16)a.x; o[1] = (bf16)a.y; o[2] = (bf16)a.z; o[3] = (bf16)a.w;
  o[4] = (bf16)b.x; o[5] = (bf16)b.y; o[6] = (bf16)b.z; o[7] = (bf16)b.w;
  *(bf16x8*)(out + i) = o;
}

// ---------------- GEMM: Y[m,n] = sum_k A[m,k] * W[n,k] + bias[n] ----------------
// MODE 2: out fp32, row-major [M,N]   (final projection)
// MODE 3: fused QKV; seg = n0>>10: seg0 Q head-major*QK_SCALE, seg1 K head-major,
//         seg2 V per-head transposed [B,H,hd,S] via LDS-transposed epilogue.
// Both grids have nwg % 8 == 0 -> simple bijective XCD swizzle.
template <int MODE>
__global__ __launch_bounds__(256, 2) void gemm_bt(
    const bf16* __restrict__ A, const bf16* __restrict__ W,
    const float* __restrict__ bias0, const float* __restrict__ bias1,
    const float* __restrict__ bias2, void* __restrict__ Out,
    int M, int N, int K, float scale) {
  __shared__ __align__(16) bf16 sm[2 * 128 * 64];
  bf16* Asl = sm;
  bf16* Bsl = sm + 128 * 64;
  const int tid = threadIdx.x;
  const int lane = tid & 63, w = tid >> 6;
  const int wr = w >> 1, wc = w & 1;
  const int r16 = lane & 15, grp = lane >> 4;

  // XCD swizzle: consecutive blocks within an XCD share A-panels
  int flat = blockIdx.y * gridDim.x + blockIdx.x;
  const int cpx = (gridDim.x * gridDim.y) >> 3;
  flat = (flat & 7) * cpx + (flat >> 3);
  const int m0 = (flat / gridDim.x) * 128;
  const int n0 = (flat % gridDim.x) * 128;

  const int seg = n0 >> 10;
  const bf16* Ab = (MODE == 3) ? A + (size_t)seg * NQKV : A;

  f32x4 acc[4][4] = {};

  const int nk = K >> 6;
  for (int t = 0; t < nk; ++t) {
    const int k0 = t << 6;
    __syncthreads();
#pragma unroll
    for (int j = 0; j < 4; ++j) {
      const int lin = j * 256 + tid;
      const int rr = lin >> 3;
      const int cc = (lin & 7) * 8;
      gload_lds16(&Ab[(size_t)(m0 + rr) * K + k0 + cc], &Asl[lin * 8]);
      gload_lds16(&W[(size_t)(n0 + rr) * K + k0 + cc], &Bsl[lin * 8]);
    }
    __syncthreads();
#pragma unroll
    for (int kk = 0; kk < 2; ++kk) {
      bf16x8 af[4], bfr[4];
#pragma unroll
      for (int m = 0; m < 4; ++m)
        af[m] = *(const bf16x8*)&Asl[(wr * 64 + m * 16 + r16) * 64 + kk * 32 + grp * 8];
#pragma unroll
      for (int n = 0; n < 4; ++n)
        bfr[n] = *(const bf16x8*)&Bsl[(wc * 64 + n * 16 + r16) * 64 + kk * 32 + grp * 8];
#pragma unroll
      for (int m = 0; m < 4; ++m)
#pragma unroll
        for (int n = 0; n < 4; ++n)
          acc[m][n] = __builtin_amdgcn_mfma_f32_16x16x32_bf16(af[m], bfr[n], acc[m][n], 0, 0, 0);
    }
  }

  const float* bp = (MODE == 3) ? (seg == 0 ? bias0 : (seg == 1 ? bias1 : bias2)) : bias0;
  const float sc = (MODE == 3) ? (seg == 0 ? scale : 1.0f) : scale;

  if (MODE == 3 && seg == 2) {
    // ---- V^T epilogue: transpose each wave's 64x64 quadrant via LDS ----
    __syncthreads();  // all Asl/Bsl readers done
    bf16* T = sm + w * (32 * 76);
    const int b = (m0 + wr * 64) >> 11;
    const int srow0 = (m0 + wr * 64) & 2047;
    bf16* base2 = (bf16*)Out + 2 * (size_t)NQKV;
#pragma unroll
    for (int p = 0; p < 2; ++p) {
#pragma unroll
      for (int nn = 0; nn < 2; ++nn) {
        const int n = 2 * p + nn;
#pragma unroll
        for (int mq = 0; mq < 4; ++mq)
#pragma unroll
          for (int r = 0; r < 4; ++r) {
            const int d_l = nn * 16 + r16;
            const int s_l = mq * 16 + grp * 4 + r;
            const int cs = (n0 + wc * 64 + n * 16 + r16) & 1023;
            T[d_l * 76 + s_l] = (bf16)(acc[mq][n][r] + bp[cs]);
          }
      }
      __syncthreads();
#pragma unroll
      for (int j = 0; j < 4; ++j) {
        const int d_l = j * 8 + (lane >> 3);
        const int scnk = lane & 7;
        const uint2 lo = *(const uint2*)&T[d_l * 76 + scnk * 8];
        const uint2 hi = *(const uint2*)&T[d_l * 76 + scnk * 8 + 4];
        const int cs = (n0 + wc * 64 + p * 32 + d_l) & 1023;
        const int hh = cs >> 6, dd = cs & 63;
        bf16* dst = base2 + ((size_t)(b * NH + hh) * HD + dd) * S_LEN + srow0 + scnk * 8;
        uint4 val; val.x = lo.x; val.y = lo.y; val.z = hi.x; val.w = hi.y;
        *(uint4*)dst = val;
      }
      __syncthreads();
    }
    return;
  }

#pragma unroll
  for (int m = 0; m < 4; ++m) {
#pragma unroll
    for (int n = 0; n < 4; ++n) {
#pragma unroll
      for (int r = 0; r < 4; ++r) {
        const int row = m0 + wr * 64 + m * 16 + grp * 4 + r;
        const int col = n0 + wc * 64 + n * 16 + r16;
        const int cs = col & 1023;
        const float v = (acc[m][n][r] + bp[cs]) * sc;
        if (MODE == 3) {  // seg 0/1: head-major
          const int b = row >> 11, s = row & 2047, h = cs >> 6, d = cs & 63;
          bf16* base = (bf16*)Out + (size_t)seg * NQKV;
          base[((size_t)(b * NH + h) * S_LEN + s) * HD + d] = (bf16)v;
        } else {
          ((float*)Out)[(size_t)row * N + col] = v;
        }
      }
    }
  }
}

// ---------------- causal flash attention: 3-buffer counted-vmcnt pipeline -------
// Block = 4 waves = one (bh, 128 q-rows). Wave w: 32 q-rows at q0+32w.
// K-tile [64 k][64 d] + V-tile [64 d][64 k] staged via global_load_lds into a
// 3-buffer ring (48 KB), XOR-swizzled source + XOR'd ds_read (rule #21).
// Pipeline (T4): 4 stage-instrs per wave per tile; `s_waitcnt vmcnt(4)` + raw
// s_barrier -- prefetch stays in flight across the barrier, never drained to 0.
// Buffer (kt+2)%3 was last read at iter kt-1, before this iter's barrier -> no
// second barrier needed. One barrier + one counted wait per tile.
// QK^T swapped mfma(K,Q), PV swapped mfma(Vt,P): softmax state lane-local.
__global__ __launch_bounds__(256, 2) void attn_fwd6(
    const bf16* __restrict__ Qh, const bf16* __restrict__ Kh,
    const bf16* __restrict__ Vt, bf16* __restrict__ AO) {
  __shared__ __align__(16) bf16 Kl[3][64 * 64];
  __shared__ __align__(16) bf16 Vl[3][64 * 64];

  const int tid = threadIdx.x;
  const int lane = tid & 63, w = tid >> 6;
  const int q31 = lane & 31, h = lane >> 5;

  // 8 XCDs x 4 heads; first half of blocks heavy-first, second half light-first
  // (pairs bid/bid+256 sum to constant work if they co-locate on a CU).
  const int bid = blockIdx.x;            // 0..511
  const int xcd = bid & 7;
  const int within = bid >> 3;           // 0..63
  const int bh = xcd * 4 + (within >> 4);
  const int cc = (within < 32) ? 15 - (within & 15) : (within & 15);
  const int q0 = cc * 128;
  const int nt = 2 * cc + 2;             // block K-tiles of 64
  const int q0w = q0 + 32 * w;
  const int nt_w = (q0w >> 6) + 1;       // this wave's live tiles
  const int qg = q0w + q31;

  const bf16* Qb = Qh + (size_t)bh * S_LEN * HD;
  const bf16* Kb = Kh + (size_t)bh * S_LEN * HD;
  const bf16* Vb = Vt + (size_t)bh * HD * S_LEN;

  // staging offsets: 512 x 16B per 8KB tile; 256 threads x 2 issues each
  int stK[2], stV[2], stL[2];
#pragma unroll
  for (int i = 0; i < 2; ++i) {
    const int lin = i * 256 + tid;
    const int row = lin >> 3;
    const int colb = (lin & 7) * 16;
    const int scol = colb ^ ((row & 7) << 4);
    stK[i] = row * HD + (scol >> 1);
    stV[i] = row * S_LEN + (scol >> 1);
    stL[i] = lin * 8;
  }

  bf16x8 qf[4];
#pragma unroll
  for (int ks = 0; ks < 4; ++ks)
    qf[ks] = *(const bf16x8*)&Qb[(size_t)qg * HD + ks * 16 + 8 * h];

  f32x16 accO[2] = {};
  float m = -1e30f, l = 0.f;
  const int swz = (q31 & 7) << 4;

  // prologue: stage tiles 0,1 into buffers 0,1 (4 vmem instrs per wave per tile)
#pragma unroll
  for (int i = 0; i < 2; ++i) {
    gload_lds16(&Kb[stK[i]], &Kl[0][stL[i]]);
    gload_lds16(&Vb[stV[i]], &Vl[0][stL[i]]);
  }
  if (nt > 1) {
#pragma unroll
    for (int i = 0; i < 2; ++i) {
      gload_lds16(&Kb[(size_t)64 * HD + stK[i]], &Kl[1][stL[i]]);
      gload_lds16(&Vb[64 + stV[i]], &Vl[1][stL[i]]);
    }
  }

  int cur = 0;
  for (int kt = 0; kt < nt; ++kt) {
    // tile kt landed when <=4 newer stage-instrs outstanding (tile kt+1's).
    if (kt + 1 < nt) asm volatile("s_waitcnt vmcnt(4)" ::: "memory");
    else             asm volatile("s_waitcnt vmcnt(0)" ::: "memory");
    __builtin_amdgcn_s_barrier();

    // stage tile kt+2 into ring slot (cur+2)%3 (its readers retired pre-barrier)
    if (kt + 2 < nt) {
      int nxt = cur + 2; if (nxt >= 3) nxt -= 3;
      const int kn = (kt + 2) << 6;
      bf16* kd = Kl[nxt];
      bf16* vd = Vl[nxt];
#pragma unroll
      for (int i = 0; i < 2; ++i) {
        gload_lds16(&Kb[(size_t)kn * HD + stK[i]], &kd[stL[i]]);
        gload_lds16(&Vb[kn + stV[i]], &vd[stL[i]]);
      }
    }

    if (kt < nt_w) {
      const int k0 = kt << 6;
      const bf16* KlC = Kl[cur];
      const bf16* VlC = Vl[cur];
      const bool diag = (kt == nt_w - 1);
      const bool skip1 = diag && (k0 + 32 > q0w + 31);

      bf16x8 kf[8];
#pragma unroll
      for (int ks = 0; ks < 4; ++ks) {
        const int c = (32 * ks + 16 * h) ^ swz;
        kf[ks] = *(const bf16x8*)((const char*)KlC + q31 * 128 + c);
      }
      if (!skip1) {
#pragma unroll
        for (int ks = 0; ks < 4; ++ks) {
          const int c = (32 * ks + 16 * h) ^ swz;
          kf[4 + ks] = *(const bf16x8*)((const char*)KlC + (32 + q31) * 128 + c);
        }
      }

      // ---- QK^T ----
      f32x16 p0 = {}, p1 = {};
      __builtin_amdgcn_s_setprio(1);
#pragma unroll
      for (int ks = 0; ks < 4; ++ks)
        p0 = __builtin_amdgcn_mfma_f32_32x32x16_bf16(kf[ks], qf[ks], p0, 0, 0, 0);
      __builtin_amdgcn_s_setprio(0);
      if (!skip1) {
        __builtin_amdgcn_s_setprio(1);
#pragma unroll
        for (int ks = 0; ks < 4; ++ks)
          p1 = __builtin_amdgcn_mfma_f32_32x32x16_bf16(kf[4 + ks], qf[ks], p1, 0, 0, 0);
        __builtin_amdgcn_s_setprio(0);
      } else {
#pragma unroll
        for (int r = 0; r < 16; ++r) p1[r] = -1e30f;
      }

      // V A-frags ks 0..1 (latency hides under softmax)
      bf16x8 vf01[4];
#pragma unroll
      for (int ks = 0; ks < 2; ++ks)
#pragma unroll
        for (int db = 0; db < 2; ++db) {
          const int c = (32 * ks + 16 * h) ^ swz;
          vf01[ks * 2 + db] =
              *(const bf16x8*)((const char*)VlC + (db * 32 + q31) * 128 + c);
        }

      // ---- causal mask (diagonal tile); key row = (r&3)+8*(r>>2)+4h ----
      if (diag) {
#pragma unroll
        for (int r = 0; r < 16; ++r) {
          const int key = k0 + (r & 3) + 8 * (r >> 2) + 4 * h;
          if (key > qg) p0[r] = -1e30f;
          if (!skip1 && key + 32 > qg) p1[r] = -1e30f;
        }
      }
      // ---- tree max ----
      float t[16];
#pragma unroll
      for (int r = 0; r < 16; ++r) t[r] = fmaxf(p0[r], p1[r]);
#pragma unroll
      for (int s = 8; s >= 1; s >>= 1)
#pragma unroll
        for (int r = 0; r < s; ++r) t[r] = fmaxf(t[r], t[r + s]);
      const float pmax = fmaxf(t[0], __shfl_xor(t[0], 32));
      // ---- defer-max (T13) ----
      if (!__all(pmax - m <= 8.0f)) {
        const float mn = fmaxf(m, pmax);
        const float alpha = exp2f(m - mn);
        m = mn;
        l *= alpha;
#pragma unroll
        for (int r = 0; r < 16; ++r) { accO[0][r] *= alpha; accO[1][r] *= alpha; }
      }
      // ---- exp + tree sum ----
      float smv[16];
#pragma unroll
      for (int r = 0; r < 16; ++r) {
        p0[r] = exp2f(p0[r] - m);
        p1[r] = exp2f(p1[r] - m);
        smv[r] = p0[r] + p1[r];
      }
#pragma unroll
      for (int s = 8; s >= 1; s >>= 1)
#pragma unroll
        for (int r = 0; r < s; ++r) smv[r] += smv[r + s];
      l += smv[0] + __shfl_xor(smv[0], 32);

      // ---- pack P -> PV B-frags via permlane32_swap ----
      unsigned pw[4][4];
#define PACK_HALF(P, o0, o1)                                                   \
  {                                                                            \
    unsigned wv[8];                                                            \
    _Pragma("unroll") for (int mm = 0; mm < 8; ++mm)                           \
        wv[mm] = packbf(P[2 * mm], P[2 * mm + 1]);                             \
    pl32swap(wv[0], wv[2]);                                                    \
    pl32swap(wv[1], wv[3]);                                                    \
    pl32swap(wv[4], wv[6]);                                                    \
    pl32swap(wv[5], wv[7]);                                                    \
    pw[o0][0] = wv[0]; pw[o0][1] = wv[1]; pw[o0][2] = wv[2]; pw[o0][3] = wv[3];\
    pw[o1][0] = wv[4]; pw[o1][1] = wv[5]; pw[o1][2] = wv[6]; pw[o1][3] = wv[7];\
  }
      PACK_HALF(p0, 0, 1)
      if (!skip1) PACK_HALF(p1, 2, 3)
#undef PACK_HALF

      bf16x8 vf23[4];
      if (!skip1) {
#pragma unroll
        for (int ks = 2; ks < 4; ++ks)
#pragma unroll
          for (int db = 0; db < 2; ++db) {
            const int c = (32 * ks + 16 * h) ^ swz;
            vf23[(ks - 2) * 2 + db] =
                *(const bf16x8*)((const char*)VlC + (db * 32 + q31) * 128 + c);
          }
      }

      // ---- PV ----
#define PV_STEP(ks, vfa)                                                       \
  {                                                                            \
    u32x4 pu = {pw[ks][0], pw[ks][1], pw[ks][2], pw[ks][3]};                   \
    const bf16x8 pf_ = __builtin_bit_cast(bf16x8, pu);                         \
    accO[0] = __builtin_amdgcn_mfma_f32_32x32x16_bf16(vfa[(ks & 1) * 2 + 0],   \
                                                      pf_, accO[0], 0, 0, 0);  \
    accO[1] = __builtin_amdgcn_mfma_f32_32x32x16_bf16(vfa[(ks & 1) * 2 + 1],   \
                                                      pf_, accO[1], 0, 0, 0);  \
  }
      __builtin_amdgcn_s_setprio(1);
      PV_STEP(0, vf01)
      PV_STEP(1, vf01)
      __builtin_amdgcn_s_setprio(0);
      if (!skip1) {
        __builtin_amdgcn_s_setprio(1);
        PV_STEP(2, vf23)
        PV_STEP(3, vf23)
        __builtin_amdgcn_s_setprio(0);
      }
#undef PV_STEP
    }

    ++cur; if (cur == 3) cur = 0;
  }

  // ---- store: O row = d = (r&3)+8*(r>>2)+4h+32db, col = q = lane&31 ----
  const float ro = 1.0f / l;
  const int b = bh >> 4, hh = bh & 15;
  bf16* orow = AO + ((size_t)(b * S_LEN + qg)) * DM + hh * HD;
#pragma unroll
  for (int db = 0; db < 2; ++db) {
#pragma unroll
    for (int mm = 0; mm < 4; ++mm) {
      bf16x4 ov;
#pragma unroll
      for (int t = 0; t < 4; ++t) ov[t] = (bf16)(accO[db][4 * mm + t] * ro);
      *(bf16x4*)&orow[db * 32 + 8 * mm + 4 * h] = ov;
    }
  }
}

// ---------------- launch ----------------
extern "C" void kernel_launch(void* const* d_in, const int* in_sizes, int n_in,
                              void* d_out, int out_size, void* d_ws, size_t ws_size,
                              hipStream_t stream) {
  const float* q  = (const float*)d_in[0];
  const float* k  = (const float*)d_in[1];
  const float* v  = (const float*)d_in[2];
  const float* Wq = (const float*)d_in[3];
  const float* bq = (const float*)d_in[4];
  const float* Wk = (const float*)d_in[5];
  const float* bk = (const float*)d_in[6];
  const float* Wv = (const float*)d_in[7];
  const float* bv = (const float*)d_in[8];
  const float* Wo = (const float*)d_in[9];
  const float* bo = (const float*)d_in[10];

  const int NTOK = 2 * S_LEN;          // 4096

  bf16* qb  = (bf16*)d_ws;             // q,k,v bf16: 3 * NQKV (consecutive)
  bf16* Wqb = qb + 3 * (size_t)NQKV;   // Wq,Wk,Wv,Wo bf16: 4 * NW (consecutive)
  bf16* Wob = Wqb + 3 * (size_t)NW;
  bf16* Qh  = Wqb + 4 * (size_t)NW;    // Qh,Kh,Vt bf16: 3 * NQKV (consecutive)
  bf16* Kh  = Qh + (size_t)NQKV;
  bf16* Vt  = Kh + (size_t)NQKV;
  bf16* AO  = Vt + (size_t)NQKV;

  const int cvt_blocks = (3 * NQKV + 4 * NW) / 8 / 256;
  cvt_all<<<cvt_blocks, 256, 0, stream>>>(q, k, v, Wq, Wk, Wv, Wo, qb);

  // fused QKV projection: M=4096, N=3072, K=1024
  gemm_bt<3><<<dim3(3 * DM / 128, NTOK / 128), 256, 0, stream>>>(
      qb, Wqb, bq, bk, bv, Qh, NTOK, 3 * DM, DM, QK_SCALE);

  // attention: 512 blocks x 256 threads, 3-buffer counted-vmcnt pipeline
  attn_fwd6<<<dim3(512), 256, 0, stream>>>(Qh, Kh, Vt, AO);

  // output projection -> fp32 d_out
  gemm_bt<2><<<dim3(DM / 128, NTOK / 128), 256, 0, stream>>>(
      AO, Wob, bo, bo, bo, d_out, NTOK, DM, DM, 1.0f);
}